// Round 2
// baseline (1620.866 us; speedup 1.0000x reference)
//
#include <hip/hip_runtime.h>
#include <stdint.h>

// Problem constants (fixed by the reference)
#define BB   512
#define NN   512
#define MROWS (BB*NN)      // 262144
#define RT   (MROWS/64)    // 4096 row tiles of 64
#define EPSV 1e-5f

typedef unsigned short u16;

// ---------- helpers ----------
__device__ __forceinline__ float read_mask(const void* mp, int r, int mode) {
  if (mode == 0) return ((const unsigned char*)mp)[r] ? 1.f : 0.f;
  if (mode == 1) return ((const unsigned int*)mp)[r] ? 1.f : 0.f;
  return ((const unsigned long long*)mp)[r] ? 1.f : 0.f;
}

__device__ __forceinline__ u16 f2bf(float f) {
  union { float f; unsigned int u; } v; v.f = f;
  unsigned int u = v.u;
  return (u16)((u + 0x7FFFu + ((u >> 16) & 1u)) >> 16);
}

__device__ __forceinline__ void up4(const ushort4 a, float* f) {
  union { unsigned int u; float f; } t;
  t.u = ((unsigned int)a.x) << 16; f[0] = t.f;
  t.u = ((unsigned int)a.y) << 16; f[1] = t.f;
  t.u = ((unsigned int)a.z) << 16; f[2] = t.f;
  t.u = ((unsigned int)a.w) << 16; f[3] = t.f;
}

__device__ __forceinline__ void unpack8(const uint4 u, float* f) {
  union { unsigned int u; float f; } t;
  t.u = u.x << 16;          f[0] = t.f;
  t.u = u.x & 0xFFFF0000u;  f[1] = t.f;
  t.u = u.y << 16;          f[2] = t.f;
  t.u = u.y & 0xFFFF0000u;  f[3] = t.f;
  t.u = u.z << 16;          f[4] = t.f;
  t.u = u.z & 0xFFFF0000u;  f[5] = t.f;
  t.u = u.w << 16;          f[6] = t.f;
  t.u = u.w & 0xFFFF0000u;  f[7] = t.f;
}

// ---------- kernel 0: detect mask element layout (uint8 / int32 / int64) ----------
__global__ void k_detect(const unsigned char* __restrict__ mu, int* __restrict__ mode) {
  __shared__ int c1, c4;
  if (threadIdx.x == 0) { c1 = 0; c4 = 0; }
  __syncthreads();
  for (int i = threadIdx.x; i < 4096; i += 256) {
    const unsigned char b = mu[i];
    if (b) {
      if ((i & 3) == 1) atomicAdd(&c1, 1);   // nonzero at byte%4==1 -> 1-byte elems
      if ((i & 7) == 4) atomicAdd(&c4, 1);   // nonzero at byte%8==4 -> 4-byte elems
    }
  }
  __syncthreads();
  if (threadIdx.x == 0) *mode = c1 ? 0 : (c4 ? 1 : 2);
}

// ---------- kernel 1: BN1 partial stats of h1 = x@W1 + b1 over valid rows ----------
__global__ __launch_bounds__(256) void k_stats1(
    const float* __restrict__ x, const void* __restrict__ mask,
    const float* __restrict__ W1, const float* __restrict__ b1,
    const int* __restrict__ modep,
    float* __restrict__ s1sum, float* __restrict__ s1sq, int* __restrict__ cntpart) {
  const int mode = *modep;
  const int tid  = threadIdx.x;
  const int c    = tid & 127;
  const int half = tid >> 7;
  const int blk  = blockIdx.x;
  float w[6];
#pragma unroll
  for (int k = 0; k < 6; ++k) w[k] = W1[k*128 + c];
  const float bb = b1[c];
  float accS = 0.f, accQ = 0.f; int cnt = 0;
  for (int i = half; i < 256; i += 2) {
    const int r = blk*256 + i;
    const float mv = read_mask(mask, r, mode);
    const float* xr = x + (size_t)r*6;
    float h = bb;
#pragma unroll
    for (int k = 0; k < 6; ++k) h = fmaf(xr[k], w[k], h);
    accS += mv*h; accQ += mv*h*h;
    if (c == 0) cnt += (mv != 0.f);
  }
  __shared__ float rs[256], rq[256];
  __shared__ int rc[2];
  rs[tid] = accS; rq[tid] = accQ;
  if (c == 0) rc[half] = cnt;
  __syncthreads();
  if (tid < 128) {
    s1sum[(size_t)blk*128 + tid] = rs[tid] + rs[tid+128];
    s1sq [(size_t)blk*128 + tid] = rq[tid] + rq[tid+128];
    if (tid == 0) cntpart[blk] = rc[0] + rc[1];
  }
}

// ---------- kernel 2: finalize BN1 -> a1 (scale), sh1 (shift), cntf ----------
__global__ __launch_bounds__(128) void k_fin1(
    const float* __restrict__ s1sum, const float* __restrict__ s1sq,
    const int* __restrict__ cntpart,
    const float* __restrict__ g1, const float* __restrict__ be1,
    float* __restrict__ a1, float* __restrict__ sh1, float* __restrict__ cntf) {
  const int c = threadIdx.x;
  float s = 0.f, q = 0.f;
  for (int b = 0; b < 1024; ++b) { s += s1sum[(size_t)b*128 + c]; q += s1sq[(size_t)b*128 + c]; }
  __shared__ float cshare;
  if (c == 0) {
    int cn = 0;
    for (int b = 0; b < 1024; ++b) cn += cntpart[b];
    float cf = (float)cn; if (cf < 1.f) cf = 1.f;
    cshare = cf; *cntf = cf;
  }
  __syncthreads();
  const float cf = cshare;
  const float mean = s / cf;
  float var = q / cf - mean*mean; if (var < 0.f) var = 0.f;
  const float a = g1[c] * rsqrtf(var + EPSV);
  a1[c]  = a;
  sh1[c] = be1[c] - mean*a;
}

// ---------- kernel 3: fused GEMM1+BN1+ReLU+GEMM2+mask -> optional h(bf16) + pool partials ----------
__global__ __launch_bounds__(256) void k_gemm2(
    const float* __restrict__ x, const void* __restrict__ mask, const int* __restrict__ modep,
    const float* __restrict__ W1, const float* __restrict__ b1,
    const float* __restrict__ a1, const float* __restrict__ sh1,
    const float* __restrict__ W2, const float* __restrict__ b2,
    u16* __restrict__ hbf, float* __restrict__ poolpart) {
  __shared__ float A_lds[128*64];   // h1n transposed: A_lds[k*64 + row]
  __shared__ float B_lds[128*64];   // W2 tile: B_lds[k*64 + col]
  const int mode = *modep;
  const int tid = threadIdx.x;
  const int rt = blockIdx.x, ct = blockIdx.y;
  const int row0 = rt*64;
  {
    const int rl = tid & 63;
    const int c0 = (tid >> 6) * 32;
    const float* xr = x + (size_t)(row0 + rl)*6;
    float xv[6];
#pragma unroll
    for (int k = 0; k < 6; ++k) xv[k] = xr[k];
    for (int c = c0; c < c0+32; ++c) {
      float h = b1[c];
#pragma unroll
      for (int k = 0; k < 6; ++k) h = fmaf(xv[k], W1[k*128 + c], h);
      h = fmaf(h, a1[c], sh1[c]);
      A_lds[c*64 + rl] = h > 0.f ? h : 0.f;
    }
  }
  for (int idx = tid; idx < 128*16; idx += 256) {
    const int k = idx >> 4, c4 = idx & 15;
    *(float4*)(B_lds + k*64 + c4*4) = *(const float4*)(W2 + (size_t)k*256 + ct*64 + c4*4);
  }
  __syncthreads();
  const int tx = tid & 15, ty = tid >> 4;
  float acc[4][4] = {};
#pragma unroll 8
  for (int k = 0; k < 128; ++k) {
    const float4 av = *(const float4*)(A_lds + k*64 + ty*4);
    const float4 bv = *(const float4*)(B_lds + k*64 + tx*4);
    const float a[4] = {av.x, av.y, av.z, av.w};
    const float b[4] = {bv.x, bv.y, bv.z, bv.w};
#pragma unroll
    for (int i = 0; i < 4; ++i)
#pragma unroll
      for (int j = 0; j < 4; ++j) acc[i][j] = fmaf(a[i], b[j], acc[i][j]);
  }
  const int gc = ct*64 + tx*4;
  float bbv[4];
#pragma unroll
  for (int j = 0; j < 4; ++j) bbv[j] = b2[gc + j];
  float cmax[4] = {-1e38f, -1e38f, -1e38f, -1e38f};
#pragma unroll
  for (int i = 0; i < 4; ++i) {
    const int row = row0 + ty*4 + i;
    const float mv = read_mask(mask, row, mode);
    float v[4];
#pragma unroll
    for (int j = 0; j < 4; ++j) {
      v[j] = (acc[i][j] + bbv[j]) * mv;
      cmax[j] = fmaxf(cmax[j], v[j]);
    }
    if (hbf) {
      ushort4 u;
      u.x = f2bf(v[0]); u.y = f2bf(v[1]); u.z = f2bf(v[2]); u.w = f2bf(v[3]);
      *(ushort4*)(hbf + (size_t)row*256 + gc) = u;
    }
  }
  __syncthreads();
  float* red = B_lds;
#pragma unroll
  for (int j = 0; j < 4; ++j) red[ty*64 + tx*4 + j] = cmax[j];
  __syncthreads();
  if (tid < 64) {
    float m = red[tid];
#pragma unroll
    for (int g = 1; g < 16; ++g) m = fmaxf(m, red[g*64 + tid]);
    const int b = rt >> 3, seg = rt & 7;
    poolpart[((size_t)(b*8 + seg))*256 + ct*64 + tid] = m;
  }
}

// ---------- kernel 4: reduce pool partials + P[b,:] = pooled[b]@W3[256:512] + b3 ----------
__global__ __launch_bounds__(256) void k_poolP(
    const float* __restrict__ poolpart, const float* __restrict__ W3,
    const float* __restrict__ b3, float* __restrict__ P) {
  __shared__ float pl[256];
  const int b = blockIdx.x, tid = threadIdx.x;
  float m = poolpart[((size_t)b*8)*256 + tid];
#pragma unroll
  for (int s = 1; s < 8; ++s) m = fmaxf(m, poolpart[((size_t)(b*8+s))*256 + tid]);
  pl[tid] = m;
  __syncthreads();
  float acc = b3[tid];
  for (int c = 0; c < 256; ++c) acc = fmaf(pl[c], W3[(size_t)(256 + c)*256 + tid], acc);
  P[(size_t)b*256 + tid] = acc;
}

// ---------- kernel 5: GEMM3 h@W3[0:256] + P[b]  -> optional h2(bf16) + BN2 stat partials ----------
__global__ __launch_bounds__(256) void k_gemm3(
    const u16* __restrict__ hbf, const void* __restrict__ mask, const int* __restrict__ modep,
    const float* __restrict__ W3, const float* __restrict__ P,
    u16* __restrict__ h2bf,
    float* __restrict__ s2sum, float* __restrict__ s2sq) {
  __shared__ float A_lds[32*64];
  __shared__ float B_lds[32*64];
  const int mode = *modep;
  const int tid = threadIdx.x;
  const int rt = blockIdx.x, ct = blockIdx.y;
  const int row0 = rt*64;
  const int tx = tid & 15, ty = tid >> 4;
  const int rlA = tid >> 2, csA = (tid & 3) * 8;
  float acc[4][4] = {};
  for (int kc = 0; kc < 256; kc += 32) {
    {
      const uint4 u = *(const uint4*)(hbf + (size_t)(row0 + rlA)*256 + kc + csA);
      float f[8]; unpack8(u, f);
#pragma unroll
      for (int j = 0; j < 8; ++j) A_lds[(csA + j)*64 + rlA] = f[j];
    }
    for (int idx = tid; idx < 512; idx += 256) {
      const int k = idx >> 4, c4 = idx & 15;
      *(float4*)(B_lds + k*64 + c4*4) = *(const float4*)(W3 + (size_t)(kc + k)*256 + ct*64 + c4*4);
    }
    __syncthreads();
#pragma unroll 8
    for (int k = 0; k < 32; ++k) {
      const float4 av = *(const float4*)(A_lds + k*64 + ty*4);
      const float4 bv = *(const float4*)(B_lds + k*64 + tx*4);
      const float a[4] = {av.x, av.y, av.z, av.w};
      const float b[4] = {bv.x, bv.y, bv.z, bv.w};
#pragma unroll
      for (int i = 0; i < 4; ++i)
#pragma unroll
        for (int j = 0; j < 4; ++j) acc[i][j] = fmaf(a[i], b[j], acc[i][j]);
    }
    __syncthreads();
  }
  const int gc = ct*64 + tx*4;
  const int b = rt >> 3;
  float Pv[4];
#pragma unroll
  for (int j = 0; j < 4; ++j) Pv[j] = P[(size_t)b*256 + gc + j];
  float msum[4] = {0,0,0,0}, msq[4] = {0,0,0,0};
#pragma unroll
  for (int i = 0; i < 4; ++i) {
    const int row = row0 + ty*4 + i;
    const float mv = read_mask(mask, row, mode);
    float v[4];
#pragma unroll
    for (int j = 0; j < 4; ++j) {
      v[j] = acc[i][j] + Pv[j];
      msum[j] += mv * v[j];
      msq[j]  += mv * v[j] * v[j];
    }
    if (h2bf) {
      ushort4 u;
      u.x = f2bf(v[0]); u.y = f2bf(v[1]); u.z = f2bf(v[2]); u.w = f2bf(v[3]);
      *(ushort4*)(h2bf + (size_t)row*256 + gc) = u;
    }
  }
  float* reds = A_lds;
  float* redq = A_lds + 1024;
#pragma unroll
  for (int j = 0; j < 4; ++j) {
    reds[ty*64 + tx*4 + j] = msum[j];
    redq[ty*64 + tx*4 + j] = msq[j];
  }
  __syncthreads();
  if (tid < 64) {
    float s = 0.f, q = 0.f;
#pragma unroll
    for (int g = 0; g < 16; ++g) { s += reds[g*64 + tid]; q += redq[g*64 + tid]; }
    s2sum[(size_t)rt*256 + ct*64 + tid] = s;
    s2sq [(size_t)rt*256 + ct*64 + tid] = q;
  }
}

// ---------- kernel 5b: coalesced slab-reduce of BN2 partials (4096 -> 64) ----------
__global__ __launch_bounds__(256) void k_red2(
    const float* __restrict__ s2sum, const float* __restrict__ s2sq,
    float* __restrict__ mids, float* __restrict__ midq) {
  const int slab = blockIdx.x;  // 0..63
  const int c = threadIdx.x;
  const float* src = blockIdx.y ? s2sq : s2sum;
  float acc = 0.f;
  for (int rt = slab*64; rt < slab*64 + 64; ++rt) acc += src[(size_t)rt*256 + c];
  (blockIdx.y ? midq : mids)[slab*256 + c] = acc;
}

// ---------- kernel 6: finalize BN2 ----------
__global__ __launch_bounds__(256) void k_fin2(
    const float* __restrict__ mids, const float* __restrict__ midq,
    const float* __restrict__ cntf,
    const float* __restrict__ g2, const float* __restrict__ be2,
    float* __restrict__ a2, float* __restrict__ sh2) {
  const int c = threadIdx.x;
  float s = 0.f, q = 0.f;
  for (int k = 0; k < 64; ++k) { s += mids[k*256 + c]; q += midq[k*256 + c]; }
  const float cf = *cntf;
  const float mean = s / cf;
  float var = q / cf - mean*mean; if (var < 0.f) var = 0.f;
  const float a = g2[c] * rsqrtf(var + EPSV);
  a2[c]  = a;
  sh2[c] = be2[c] - mean*a;
}

// ---------- kernel 7 (tier 2): BN2+ReLU+GEMM4+mask from stored h2 ----------
__global__ __launch_bounds__(256) void k_gemm4(
    const u16* __restrict__ h2bf, const void* __restrict__ mask, const int* __restrict__ modep,
    const float* __restrict__ a2, const float* __restrict__ sh2,
    const float* __restrict__ W4, const float* __restrict__ b4,
    float* __restrict__ outpart) {
  __shared__ float A_lds[32*64];
  __shared__ float B_lds[32*64];
  __shared__ float a2l[256], s2l[256];
  const int mode = *modep;
  const int tid = threadIdx.x;
  a2l[tid] = a2[tid]; s2l[tid] = sh2[tid];
  const int rt = blockIdx.x, ct = blockIdx.y;
  const int row0 = rt*64;
  const int tx = tid & 15, ty = tid >> 4;
  const int rlA = tid >> 2, csA = (tid & 3) * 8;
  float acc[4][4] = {};
  __syncthreads();
  for (int kc = 0; kc < 256; kc += 32) {
    {
      const uint4 u = *(const uint4*)(h2bf + (size_t)(row0 + rlA)*256 + kc + csA);
      float f[8]; unpack8(u, f);
#pragma unroll
      for (int j = 0; j < 8; ++j) {
        const int kk = kc + csA + j;
        const float z = fmaf(f[j], a2l[kk], s2l[kk]);
        A_lds[(csA + j)*64 + rlA] = z > 0.f ? z : 0.f;
      }
    }
    for (int idx = tid; idx < 512; idx += 256) {
      const int k = idx >> 4, c4 = idx & 15;
      *(float4*)(B_lds + k*64 + c4*4) = *(const float4*)(W4 + (size_t)(kc + k)*128 + ct*64 + c4*4);
    }
    __syncthreads();
#pragma unroll 8
    for (int k = 0; k < 32; ++k) {
      const float4 av = *(const float4*)(A_lds + k*64 + ty*4);
      const float4 bv = *(const float4*)(B_lds + k*64 + tx*4);
      const float a[4] = {av.x, av.y, av.z, av.w};
      const float b[4] = {bv.x, bv.y, bv.z, bv.w};
#pragma unroll
      for (int i = 0; i < 4; ++i)
#pragma unroll
        for (int j = 0; j < 4; ++j) acc[i][j] = fmaf(a[i], b[j], acc[i][j]);
    }
    __syncthreads();
  }
  const int gc = ct*64 + tx*4;
  float bbv[4];
#pragma unroll
  for (int j = 0; j < 4; ++j) bbv[j] = b4[gc + j];
  float cmax[4] = {-1e38f, -1e38f, -1e38f, -1e38f};
#pragma unroll
  for (int i = 0; i < 4; ++i) {
    const int row = row0 + ty*4 + i;
    const float mv = read_mask(mask, row, mode);
#pragma unroll
    for (int j = 0; j < 4; ++j) {
      const float v = (acc[i][j] + bbv[j]) * mv;
      cmax[j] = fmaxf(cmax[j], v);
    }
  }
  float* red = B_lds;
#pragma unroll
  for (int j = 0; j < 4; ++j) red[ty*64 + tx*4 + j] = cmax[j];
  __syncthreads();
  if (tid < 64) {
    float m = red[tid];
#pragma unroll
    for (int g = 1; g < 16; ++g) m = fmaxf(m, red[g*64 + tid]);
    const int b = rt >> 3, seg = rt & 7;
    outpart[((size_t)(b*8 + seg))*128 + ct*64 + tid] = m;
  }
}

// ---------- tier 1: fused GEMM3(recompute)+BN2+ReLU+GEMM4 from stored h ----------
__global__ __launch_bounds__(256) void k_gemm34_med(
    const u16* __restrict__ hbf, const void* __restrict__ mask, const int* __restrict__ modep,
    const float* __restrict__ W3, const float* __restrict__ P,
    const float* __restrict__ a2, const float* __restrict__ sh2,
    const float* __restrict__ W4, const float* __restrict__ b4,
    float* __restrict__ outpart) {
  __shared__ u16   As[256*64];   // 32 KB  [k][row] bf16 h tile
  __shared__ float Bs[32*64];    // 8 KB   staging
  __shared__ float h2n[64*64];   // 16 KB  [k2][row] f32 (post BN2+ReLU)
  __shared__ float Pl[256], a2l[256], s2l[256];
  const int mode = *modep;
  const int tid = threadIdx.x;
  const int rt = blockIdx.x;
  const int row0 = rt*64;
  const int b = rt >> 3;
  Pl[tid] = P[(size_t)b*256 + tid];
  a2l[tid] = a2[tid]; s2l[tid] = sh2[tid];
  // stage h tile transposed to [k][row]
  {
    const int r = tid & 63;
    const int kg = (tid >> 6) * 64;
    for (int kk = 0; kk < 64; kk += 8) {
      const uint4 u = *(const uint4*)(hbf + (size_t)(row0 + r)*256 + kg + kk);
      const u16* us = (const u16*)&u;
#pragma unroll
      for (int j = 0; j < 8; ++j) As[(kg + kk + j)*64 + r] = us[j];
    }
  }
  __syncthreads();
  const int ux = tid & 15, uy = tid >> 4;
  const int ry = (tid >> 5) * 8;
  const int cx = (tid & 31) * 4;
  float oacc[8][4] = {};
  for (int c2 = 0; c2 < 256; c2 += 64) {
    float acc[4][4] = {};
    for (int kc = 0; kc < 256; kc += 32) {
      for (int idx = tid; idx < 512; idx += 256) {
        const int k = idx >> 4, c4 = idx & 15;
        *(float4*)(Bs + k*64 + c4*4) = *(const float4*)(W3 + (size_t)(kc + k)*256 + c2 + c4*4);
      }
      __syncthreads();
#pragma unroll 8
      for (int k = 0; k < 32; ++k) {
        const ushort4 a4 = *(const ushort4*)(As + (kc + k)*64 + uy*4);
        float af[4]; up4(a4, af);
        const float4 bv = *(const float4*)(Bs + k*64 + ux*4);
        const float bf[4] = {bv.x, bv.y, bv.z, bv.w};
#pragma unroll
        for (int i = 0; i < 4; ++i)
#pragma unroll
          for (int j = 0; j < 4; ++j) acc[i][j] = fmaf(af[i], bf[j], acc[i][j]);
      }
      __syncthreads();
    }
    // BN2 + ReLU -> h2n [k2][row]
#pragma unroll
    for (int j = 0; j < 4; ++j) {
      const int cc = c2 + ux*4 + j;
      const float aa = a2l[cc], ss = s2l[cc], pp = Pl[cc];
#pragma unroll
      for (int i = 0; i < 4; ++i) {
        float v = fmaf(acc[i][j] + pp, aa, ss);
        h2n[(ux*4 + j)*64 + uy*4 + i] = v > 0.f ? v : 0.f;
      }
    }
    __syncthreads();
    // GEMM4 partial accumulate: oacc[row][col] += sum_k2 h2n[k2][row]*W4[c2+k2][col]
#pragma unroll 4
    for (int k2 = 0; k2 < 64; ++k2) {
      const float4 r0 = *(const float4*)(h2n + k2*64 + ry);
      const float4 r1 = *(const float4*)(h2n + k2*64 + ry + 4);
      const float4 w  = *(const float4*)(W4 + (size_t)(c2 + k2)*128 + cx);
      const float rr[8] = {r0.x, r0.y, r0.z, r0.w, r1.x, r1.y, r1.z, r1.w};
      const float wf[4] = {w.x, w.y, w.z, w.w};
#pragma unroll
      for (int i = 0; i < 8; ++i)
#pragma unroll
        for (int j = 0; j < 4; ++j) oacc[i][j] = fmaf(rr[i], wf[j], oacc[i][j]);
    }
    __syncthreads();
  }
  // epilogue: +b4, mask, column max
  float bb4[4];
#pragma unroll
  for (int j = 0; j < 4; ++j) bb4[j] = b4[cx + j];
  float cmax[4] = {-1e38f, -1e38f, -1e38f, -1e38f};
#pragma unroll
  for (int i = 0; i < 8; ++i) {
    const float mv = read_mask(mask, row0 + ry + i, mode);
#pragma unroll
    for (int j = 0; j < 4; ++j) {
      const float v = (oacc[i][j] + bb4[j]) * mv;
      cmax[j] = fmaxf(cmax[j], v);
    }
  }
  float* red = Bs;
#pragma unroll
  for (int j = 0; j < 4; ++j) red[(tid >> 5)*128 + cx + j] = cmax[j];
  __syncthreads();
  if (tid < 128) {
    float m = red[tid];
#pragma unroll
    for (int g = 1; g < 8; ++g) m = fmaxf(m, red[g*128 + tid]);
    const int seg = rt & 7;
    outpart[((size_t)(b*8 + seg))*128 + tid] = m;
  }
}

// ---------- tier 0 shared: build masked h tile (bf16, [k][row]) from x ----------
__device__ __forceinline__ void build_h_tile(
    const float* __restrict__ x, const void* __restrict__ mask, int mode,
    const float* __restrict__ W1, const float* __restrict__ b1,
    const float* __restrict__ a1, const float* __restrict__ sh1,
    const float* __restrict__ W2, const float* __restrict__ b2,
    int row0, int tid,
    u16* h1n /*[128][64]*/, float* Bs /*[32*64]*/, u16* As /*[256][64]*/) {
  {
    const int rl = tid & 63;
    const int c0 = (tid >> 6) * 32;
    const float* xr = x + (size_t)(row0 + rl)*6;
    float xv[6];
#pragma unroll
    for (int k = 0; k < 6; ++k) xv[k] = xr[k];
    for (int c = c0; c < c0 + 32; ++c) {
      float h = b1[c];
#pragma unroll
      for (int k = 0; k < 6; ++k) h = fmaf(xv[k], W1[k*128 + c], h);
      h = fmaf(h, a1[c], sh1[c]);
      h1n[c*64 + rl] = f2bf(h > 0.f ? h : 0.f);
    }
  }
  __syncthreads();
  const int ux = tid & 15, uy = tid >> 4;
  float mv[4];
#pragma unroll
  for (int i = 0; i < 4; ++i) mv[i] = read_mask(mask, row0 + uy*4 + i, mode);
  for (int c2 = 0; c2 < 256; c2 += 64) {
    float acc[4][4] = {};
    for (int kc = 0; kc < 128; kc += 32) {
      for (int idx = tid; idx < 512; idx += 256) {
        const int k = idx >> 4, c4 = idx & 15;
        *(float4*)(Bs + k*64 + c4*4) = *(const float4*)(W2 + (size_t)(kc + k)*256 + c2 + c4*4);
      }
      __syncthreads();
#pragma unroll 8
      for (int k = 0; k < 32; ++k) {
        const ushort4 a4 = *(const ushort4*)(h1n + (kc + k)*64 + uy*4);
        float af[4]; up4(a4, af);
        const float4 bv = *(const float4*)(Bs + k*64 + ux*4);
        const float bf[4] = {bv.x, bv.y, bv.z, bv.w};
#pragma unroll
        for (int i = 0; i < 4; ++i)
#pragma unroll
          for (int j = 0; j < 4; ++j) acc[i][j] = fmaf(af[i], bf[j], acc[i][j]);
      }
      __syncthreads();
    }
#pragma unroll
    for (int j = 0; j < 4; ++j) {
      const float bb = b2[c2 + ux*4 + j];
#pragma unroll
      for (int i = 0; i < 4; ++i) {
        const float v = (acc[i][j] + bb) * mv[i];
        As[(c2 + ux*4 + j)*64 + uy*4 + i] = f2bf(v);
      }
    }
  }
  __syncthreads();
}

// ---------- tier 0: h recompute + GEMM3 + BN2 stat partials ----------
__global__ __launch_bounds__(256) void k_stats2_small(
    const float* __restrict__ x, const void* __restrict__ mask, const int* __restrict__ modep,
    const float* __restrict__ W1, const float* __restrict__ b1,
    const float* __restrict__ a1, const float* __restrict__ sh1,
    const float* __restrict__ W2, const float* __restrict__ b2,
    const float* __restrict__ W3, const float* __restrict__ P,
    float* __restrict__ s2sum, float* __restrict__ s2sq) {
  __shared__ u16   As[256*64];  // 32 KB
  __shared__ float Bs[32*64];   // 8 KB
  __shared__ float un[64*64];   // 16 KB: h1n (bf16 view) then reds/redq
  __shared__ float Pl[256];
  const int mode = *modep;
  const int tid = threadIdx.x;
  const int rt = blockIdx.x;
  const int row0 = rt*64;
  const int b = rt >> 3;
  Pl[tid] = P[(size_t)b*256 + tid];
  build_h_tile(x, mask, mode, W1, b1, a1, sh1, W2, b2, row0, tid, (u16*)un, Bs, As);
  const int ux = tid & 15, uy = tid >> 4;
  float mv[4];
#pragma unroll
  for (int i = 0; i < 4; ++i) mv[i] = read_mask(mask, row0 + uy*4 + i, mode);
  float* reds = un;
  float* redq = un + 1024;
  for (int c2 = 0; c2 < 256; c2 += 64) {
    float acc[4][4] = {};
    for (int kc = 0; kc < 256; kc += 32) {
      for (int idx = tid; idx < 512; idx += 256) {
        const int k = idx >> 4, c4 = idx & 15;
        *(float4*)(Bs + k*64 + c4*4) = *(const float4*)(W3 + (size_t)(kc + k)*256 + c2 + c4*4);
      }
      __syncthreads();
#pragma unroll 8
      for (int k = 0; k < 32; ++k) {
        const ushort4 a4 = *(const ushort4*)(As + (kc + k)*64 + uy*4);
        float af[4]; up4(a4, af);
        const float4 bv = *(const float4*)(Bs + k*64 + ux*4);
        const float bf[4] = {bv.x, bv.y, bv.z, bv.w};
#pragma unroll
        for (int i = 0; i < 4; ++i)
#pragma unroll
          for (int j = 0; j < 4; ++j) acc[i][j] = fmaf(af[i], bf[j], acc[i][j]);
      }
      __syncthreads();
    }
    float msum[4] = {0,0,0,0}, msq[4] = {0,0,0,0};
#pragma unroll
    for (int j = 0; j < 4; ++j) {
      const float pp = Pl[c2 + ux*4 + j];
#pragma unroll
      for (int i = 0; i < 4; ++i) {
        const float v = acc[i][j] + pp;
        msum[j] += mv[i] * v;
        msq[j]  += mv[i] * v * v;
      }
    }
#pragma unroll
    for (int j = 0; j < 4; ++j) {
      reds[uy*64 + ux*4 + j] = msum[j];
      redq[uy*64 + ux*4 + j] = msq[j];
    }
    __syncthreads();
    if (tid < 64) {
      float s = 0.f, q = 0.f;
#pragma unroll
      for (int g = 0; g < 16; ++g) { s += reds[g*64 + tid]; q += redq[g*64 + tid]; }
      s2sum[(size_t)rt*256 + c2 + tid] = s;
      s2sq [(size_t)rt*256 + c2 + tid] = q;
    }
    __syncthreads();
  }
}

// ---------- tier 0: h recompute + GEMM3 + BN2+ReLU + GEMM4 ----------
__global__ __launch_bounds__(256) void k_gemm34_small(
    const float* __restrict__ x, const void* __restrict__ mask, const int* __restrict__ modep,
    const float* __restrict__ W1, const float* __restrict__ b1,
    const float* __restrict__ a1, const float* __restrict__ sh1,
    const float* __restrict__ W2, const float* __restrict__ b2,
    const float* __restrict__ W3, const float* __restrict__ P,
    const float* __restrict__ a2, const float* __restrict__ sh2,
    const float* __restrict__ W4, const float* __restrict__ b4,
    float* __restrict__ outpart) {
  __shared__ u16   As[256*64];  // 32 KB
  __shared__ float Bs[32*64];   // 8 KB
  __shared__ float un[64*64];   // 16 KB: h1n then h2n
  __shared__ float Pl[256], a2l[256], s2l[256];
  const int mode = *modep;
  const int tid = threadIdx.x;
  const int rt = blockIdx.x;
  const int row0 = rt*64;
  const int b = rt >> 3;
  Pl[tid] = P[(size_t)b*256 + tid];
  a2l[tid] = a2[tid]; s2l[tid] = sh2[tid];
  build_h_tile(x, mask, mode, W1, b1, a1, sh1, W2, b2, row0, tid, (u16*)un, Bs, As);
  float* h2n = un;
  const int ux = tid & 15, uy = tid >> 4;
  const int ry = (tid >> 5) * 8;
  const int cx = (tid & 31) * 4;
  float oacc[8][4] = {};
  for (int c2 = 0; c2 < 256; c2 += 64) {
    float acc[4][4] = {};
    for (int kc = 0; kc < 256; kc += 32) {
      for (int idx = tid; idx < 512; idx += 256) {
        const int k = idx >> 4, c4 = idx & 15;
        *(float4*)(Bs + k*64 + c4*4) = *(const float4*)(W3 + (size_t)(kc + k)*256 + c2 + c4*4);
      }
      __syncthreads();
#pragma unroll 8
      for (int k = 0; k < 32; ++k) {
        const ushort4 a4 = *(const ushort4*)(As + (kc + k)*64 + uy*4);
        float af[4]; up4(a4, af);
        const float4 bv = *(const float4*)(Bs + k*64 + ux*4);
        const float bf[4] = {bv.x, bv.y, bv.z, bv.w};
#pragma unroll
        for (int i = 0; i < 4; ++i)
#pragma unroll
          for (int j = 0; j < 4; ++j) acc[i][j] = fmaf(af[i], bf[j], acc[i][j]);
      }
      __syncthreads();
    }
#pragma unroll
    for (int j = 0; j < 4; ++j) {
      const int cc = c2 + ux*4 + j;
      const float aa = a2l[cc], ss = s2l[cc], pp = Pl[cc];
#pragma unroll
      for (int i = 0; i < 4; ++i) {
        float v = fmaf(acc[i][j] + pp, aa, ss);
        h2n[(ux*4 + j)*64 + uy*4 + i] = v > 0.f ? v : 0.f;
      }
    }
    __syncthreads();
#pragma unroll 4
    for (int k2 = 0; k2 < 64; ++k2) {
      const float4 r0 = *(const float4*)(h2n + k2*64 + ry);
      const float4 r1 = *(const float4*)(h2n + k2*64 + ry + 4);
      const float4 w  = *(const float4*)(W4 + (size_t)(c2 + k2)*128 + cx);
      const float rr[8] = {r0.x, r0.y, r0.z, r0.w, r1.x, r1.y, r1.z, r1.w};
      const float wf[4] = {w.x, w.y, w.z, w.w};
#pragma unroll
      for (int i = 0; i < 8; ++i)
#pragma unroll
        for (int j = 0; j < 4; ++j) oacc[i][j] = fmaf(rr[i], wf[j], oacc[i][j]);
    }
    __syncthreads();
  }
  float bb4[4];
#pragma unroll
  for (int j = 0; j < 4; ++j) bb4[j] = b4[cx + j];
  float cmax[4] = {-1e38f, -1e38f, -1e38f, -1e38f};
#pragma unroll
  for (int i = 0; i < 8; ++i) {
    const float mv = read_mask(mask, row0 + ry + i, mode);
#pragma unroll
    for (int j = 0; j < 4; ++j) {
      const float v = (oacc[i][j] + bb4[j]) * mv;
      cmax[j] = fmaxf(cmax[j], v);
    }
  }
  float* red = Bs;
#pragma unroll
  for (int j = 0; j < 4; ++j) red[(tid >> 5)*128 + cx + j] = cmax[j];
  __syncthreads();
  if (tid < 128) {
    float m = red[tid];
#pragma unroll
    for (int g = 1; g < 8; ++g) m = fmaxf(m, red[g*128 + tid]);
    const int seg = rt & 7;
    outpart[((size_t)(b*8 + seg))*128 + tid] = m;
  }
}

// ---------- kernel 8: reduce 8 segment maxima -> out[b,e] ----------
__global__ __launch_bounds__(256) void k_outred(
    const float* __restrict__ outpart, float* __restrict__ out) {
  const int idx = blockIdx.x*256 + threadIdx.x;  // < 65536
  const int b = idx >> 7, e = idx & 127;
  float m = outpart[((size_t)b*8)*128 + e];
#pragma unroll
  for (int s = 1; s < 8; ++s) m = fmaxf(m, outpart[((size_t)(b*8 + s))*128 + e]);
  out[idx] = m;
}

extern "C" void kernel_launch(void* const* d_in, const int* in_sizes, int n_in,
                              void* d_out, int out_size, void* d_ws, size_t ws_size,
                              hipStream_t stream) {
  const float* x    = (const float*)d_in[0];
  const void*  mask = d_in[1];
  const float* W1   = (const float*)d_in[2];
  const float* b1   = (const float*)d_in[3];
  const float* g1   = (const float*)d_in[4];
  const float* be1  = (const float*)d_in[5];
  const float* W2   = (const float*)d_in[6];
  const float* b2   = (const float*)d_in[7];
  const float* W3   = (const float*)d_in[8];
  const float* b3   = (const float*)d_in[9];
  const float* g2   = (const float*)d_in[10];
  const float* be2  = (const float*)d_in[11];
  const float* W4   = (const float*)d_in[12];
  const float* b4   = (const float*)d_in[13];
  float* out = (float*)d_out;

  const size_t HBF_BYTES = (size_t)MROWS * 256 * 2;  // 128 MiB
  // tier by available workspace (constant across calls -> graph-safe)
  const int tier = (ws_size >= ((size_t)300 << 20)) ? 2
                 : (ws_size >= ((size_t)160 << 20)) ? 1 : 0;

  char* ws = (char*)d_ws;
  size_t off = 0;
  auto take = [&](size_t bytes) -> char* {
    char* p = ws + off;
    off = (off + bytes + 255) & ~(size_t)255;
    return p;
  };
  u16* hbf  = (tier >= 1) ? (u16*)take(HBF_BYTES) : nullptr;
  u16* h2bf = (tier == 2) ? (u16*)take(HBF_BYTES) : nullptr;
  float* s1sum   = (float*)take((size_t)1024*128*4);
  float* s1sq    = (float*)take((size_t)1024*128*4);
  int*   cntpart = (int*)  take((size_t)1024*4);
  float* a1      = (float*)take(128*4);
  float* sh1     = (float*)take(128*4);
  float* cntf    = (float*)take(256);
  float* poolpart= (float*)take((size_t)512*8*256*4);
  float* P       = (float*)take((size_t)512*256*4);
  float* s2sum   = (float*)take((size_t)4096*256*4);
  float* s2sq    = (float*)take((size_t)4096*256*4);
  float* mids    = (float*)take((size_t)64*256*4);
  float* midq    = (float*)take((size_t)64*256*4);
  float* a2      = (float*)take(256*4);
  float* sh2     = (float*)take(256*4);
  float* outpart = (float*)take((size_t)512*8*128*4);
  int*   modep   = (int*)  take(256);

  k_detect<<<1, 256, 0, stream>>>((const unsigned char*)mask, modep);
  k_stats1<<<1024, 256, 0, stream>>>(x, mask, W1, b1, modep, s1sum, s1sq, cntpart);
  k_fin1<<<1, 128, 0, stream>>>(s1sum, s1sq, cntpart, g1, be1, a1, sh1, cntf);
  k_gemm2<<<dim3(RT, 4), 256, 0, stream>>>(x, mask, modep, W1, b1, a1, sh1, W2, b2, hbf, poolpart);
  k_poolP<<<512, 256, 0, stream>>>(poolpart, W3, b3, P);
  if (tier >= 1) {
    k_gemm3<<<dim3(RT, 4), 256, 0, stream>>>(hbf, mask, modep, W3, P, h2bf, s2sum, s2sq);
  } else {
    k_stats2_small<<<RT, 256, 0, stream>>>(x, mask, modep, W1, b1, a1, sh1, W2, b2, W3, P, s2sum, s2sq);
  }
  k_red2<<<dim3(64, 2), 256, 0, stream>>>(s2sum, s2sq, mids, midq);
  k_fin2<<<1, 256, 0, stream>>>(mids, midq, cntf, g2, be2, a2, sh2);
  if (tier == 2) {
    k_gemm4<<<dim3(RT, 2), 256, 0, stream>>>(h2bf, mask, modep, a2, sh2, W4, b4, outpart);
  } else if (tier == 1) {
    k_gemm34_med<<<RT, 256, 0, stream>>>(hbf, mask, modep, W3, P, a2, sh2, W4, b4, outpart);
  } else {
    k_gemm34_small<<<RT, 256, 0, stream>>>(x, mask, modep, W1, b1, a1, sh1, W2, b2, W3, P, a2, sh2, W4, b4, outpart);
  }
  k_outred<<<256, 256, 0, stream>>>(outpart, out);
}

// Round 3
// 535.470 us; speedup vs baseline: 3.0270x; 3.0270x over previous
//
#include <hip/hip_runtime.h>
#include <stdint.h>

// Problem constants (fixed by the reference)
#define BB   512
#define NN   512
#define MROWS (BB*NN)      // 262144
#define RT   (MROWS/64)    // 4096 row tiles of 64
#define EPSV 1e-5f

typedef unsigned short u16;
typedef __attribute__((ext_vector_type(8))) short bf16x8;   // 8 bf16 = 4 VGPRs
typedef __attribute__((ext_vector_type(4))) float f32x4;

// ---------- helpers ----------
__device__ __forceinline__ float read_mask(const void* mp, int r, int mode) {
  if (mode == 0) return ((const unsigned char*)mp)[r] ? 1.f : 0.f;
  if (mode == 1) return ((const unsigned int*)mp)[r] ? 1.f : 0.f;
  return ((const unsigned long long*)mp)[r] ? 1.f : 0.f;
}

__device__ __forceinline__ u16 f2bf(float f) {
  union { float f; unsigned int u; } v; v.f = f;
  unsigned int u = v.u;
  return (u16)((u + 0x7FFFu + ((u >> 16) & 1u)) >> 16);
}

__device__ __forceinline__ float bf2f(u16 b) {
  union { unsigned int u; float f; } t;
  t.u = ((unsigned int)b) << 16;
  return t.f;
}

// ---------- kernel 0: detect mask element layout (uint8 / int32 / int64) ----------
__global__ void k_detect(const unsigned char* __restrict__ mu, int* __restrict__ mode) {
  __shared__ int c1, c4;
  if (threadIdx.x == 0) { c1 = 0; c4 = 0; }
  __syncthreads();
  for (int i = threadIdx.x; i < 4096; i += 256) {
    const unsigned char b = mu[i];
    if (b) {
      if ((i & 3) == 1) atomicAdd(&c1, 1);
      if ((i & 7) == 4) atomicAdd(&c4, 1);
    }
  }
  __syncthreads();
  if (threadIdx.x == 0) *mode = c1 ? 0 : (c4 ? 1 : 2);
}

// ---------- weight prep: bf16 transposed copies Wt[n][k] ----------
__global__ __launch_bounds__(256) void k_prep(
    const float* __restrict__ W2, const float* __restrict__ W3, const float* __restrict__ W4,
    u16* __restrict__ w2t, u16* __restrict__ w3t, u16* __restrict__ w4t) {
  const int idx = blockIdx.x*256 + threadIdx.x;  // < 131072
  if (idx < 32768) {                 // W2t [256 n][128 k]
    const int n = idx >> 7, k = idx & 127;
    w2t[idx] = f2bf(W2[(size_t)k*256 + n]);
  } else if (idx < 98304) {          // W3t [256 n][256 k] (first half of W3 rows)
    const int j = idx - 32768;
    const int n = j >> 8, k = j & 255;
    w3t[j] = f2bf(W3[(size_t)k*256 + n]);
  } else {                           // W4t [128 n][256 k]
    const int j = idx - 98304;
    const int n = j >> 8, k = j & 255;
    w4t[j] = f2bf(W4[(size_t)k*128 + n]);
  }
}

// ---------- kernel 1: BN1 partial stats of h1 = x@W1 + b1 over valid rows ----------
__global__ __launch_bounds__(256) void k_stats1(
    const float* __restrict__ x, const void* __restrict__ mask,
    const float* __restrict__ W1, const float* __restrict__ b1,
    const int* __restrict__ modep,
    float* __restrict__ s1sum, float* __restrict__ s1sq, int* __restrict__ cntpart) {
  const int mode = *modep;
  const int tid  = threadIdx.x;
  const int c    = tid & 127;
  const int half = tid >> 7;
  const int blk  = blockIdx.x;
  float w[6];
#pragma unroll
  for (int k = 0; k < 6; ++k) w[k] = W1[k*128 + c];
  const float bb = b1[c];
  float accS = 0.f, accQ = 0.f; int cnt = 0;
  for (int i = half; i < 256; i += 2) {
    const int r = blk*256 + i;
    const float mv = read_mask(mask, r, mode);
    const float* xr = x + (size_t)r*6;
    float h = bb;
#pragma unroll
    for (int k = 0; k < 6; ++k) h = fmaf(xr[k], w[k], h);
    accS += mv*h; accQ += mv*h*h;
    if (c == 0) cnt += (mv != 0.f);
  }
  __shared__ float rs[256], rq[256];
  __shared__ int rc[2];
  rs[tid] = accS; rq[tid] = accQ;
  if (c == 0) rc[half] = cnt;
  __syncthreads();
  if (tid < 128) {
    s1sum[(size_t)blk*128 + tid] = rs[tid] + rs[tid+128];
    s1sq [(size_t)blk*128 + tid] = rq[tid] + rq[tid+128];
    if (tid == 0) cntpart[blk] = rc[0] + rc[1];
  }
}

// ---------- kernel 2: finalize BN1 ----------
__global__ __launch_bounds__(128) void k_fin1(
    const float* __restrict__ s1sum, const float* __restrict__ s1sq,
    const int* __restrict__ cntpart,
    const float* __restrict__ g1, const float* __restrict__ be1,
    float* __restrict__ a1, float* __restrict__ sh1, float* __restrict__ cntf) {
  const int c = threadIdx.x;
  float s = 0.f, q = 0.f;
  for (int b = 0; b < 1024; ++b) { s += s1sum[(size_t)b*128 + c]; q += s1sq[(size_t)b*128 + c]; }
  __shared__ float cshare;
  if (c == 0) {
    int cn = 0;
    for (int b = 0; b < 1024; ++b) cn += cntpart[b];
    float cf = (float)cn; if (cf < 1.f) cf = 1.f;
    cshare = cf; *cntf = cf;
  }
  __syncthreads();
  const float cf = cshare;
  const float mean = s / cf;
  float var = q / cf - mean*mean; if (var < 0.f) var = 0.f;
  const float a = g1[c] * rsqrtf(var + EPSV);
  a1[c]  = a;
  sh1[c] = be1[c] - mean*a;
}

// ---------- kernel 3 (MFMA): GEMM1+BN1+ReLU+GEMM2+mask -> h(bf16) + pool partials ----
// block: 256 thr / 4 waves; 64 rows x 256 cols. wave w: cols [64w,64w+64).
__global__ __launch_bounds__(256) void k_gemm2_m(
    const float* __restrict__ x, const void* __restrict__ mask, const int* __restrict__ modep,
    const float* __restrict__ W1, const float* __restrict__ b1,
    const float* __restrict__ a1, const float* __restrict__ sh1,
    const u16* __restrict__ W2t, const float* __restrict__ b2,
    u16* __restrict__ hbf, float* __restrict__ poolpart) {
  __shared__ u16 h1[64*136];    // A tile [row][k], pitch 136 (17 KB)
  __shared__ u16 outt[64*264];  // out tile [row][col], pitch 264 (33.8 KB)
  __shared__ float mk[64];
  const int mode = *modep;
  const int tid = threadIdx.x;
  const int rt = blockIdx.x;
  const int row0 = rt*64;
  if (tid < 64) mk[tid] = read_mask(mask, row0 + tid, mode);
  // h1n tile (64x128) via VALU (K=6), bf16 into LDS
  {
    const int rl = tid & 63;
    const int c0 = (tid >> 6) * 32;
    const float* xr = x + (size_t)(row0 + rl)*6;
    float xv[6];
#pragma unroll
    for (int k = 0; k < 6; ++k) xv[k] = xr[k];
    for (int c = c0; c < c0+32; ++c) {
      float h = b1[c];
#pragma unroll
      for (int k = 0; k < 6; ++k) h = fmaf(xv[k], W1[k*128 + c], h);
      h = fmaf(h, a1[c], sh1[c]);
      h1[rl*136 + c] = f2bf(h > 0.f ? h : 0.f);
    }
  }
  __syncthreads();
  const int wave = tid >> 6, lane = tid & 63;
  const int lr = lane & 15, lq = lane >> 4;
  f32x4 acc[4][4];
#pragma unroll
  for (int r = 0; r < 4; ++r)
#pragma unroll
    for (int c = 0; c < 4; ++c) acc[r][c] = (f32x4){0.f,0.f,0.f,0.f};
  for (int kc = 0; kc < 128; kc += 32) {
    bf16x8 afr[4];
#pragma unroll
    for (int r = 0; r < 4; ++r)
      afr[r] = *(const bf16x8*)(h1 + (r*16 + lr)*136 + kc + lq*8);
#pragma unroll
    for (int c = 0; c < 4; ++c) {
      const bf16x8 bfr = *(const bf16x8*)(W2t + (size_t)(wave*64 + c*16 + lr)*128 + kc + lq*8);
#pragma unroll
      for (int r = 0; r < 4; ++r)
        acc[r][c] = __builtin_amdgcn_mfma_f32_16x16x32_bf16(afr[r], bfr, acc[r][c], 0, 0, 0);
    }
  }
  // epilogue: +b2, mask, bf16 into outt (C layout: row=(lq*4+i), col=ct*16+lr)
#pragma unroll
  for (int c = 0; c < 4; ++c) {
    const int col = wave*64 + c*16 + lr;
    const float bb = b2[col];
#pragma unroll
    for (int r = 0; r < 4; ++r) {
#pragma unroll
      for (int i = 0; i < 4; ++i) {
        const int row = r*16 + lq*4 + i;
        outt[row*264 + col] = f2bf((acc[r][c][i] + bb) * mk[row]);
      }
    }
  }
  __syncthreads();
  // pool col-max (zeros from masked rows participate, matching torch)
  {
    const int col = tid;
    float m = -1e38f;
    for (int row = 0; row < 64; ++row) m = fmaxf(m, bf2f(outt[row*264 + col]));
    const int b = rt >> 3, seg = rt & 7;
    poolpart[((size_t)(b*8 + seg))*256 + col] = m;
  }
  // coalesced store of tile to hbf
  for (int it = tid; it < 64*32; it += 256) {
    const int row = it >> 5, c8 = it & 31;
    *(uint4*)(hbf + (size_t)(row0 + row)*256 + c8*8) = *(const uint4*)(outt + row*264 + c8*8);
  }
}

// ---------- kernel 4: reduce pool partials + P[b,:] = pooled[b]@W3[256:512] + b3 ----------
__global__ __launch_bounds__(256) void k_poolP(
    const float* __restrict__ poolpart, const float* __restrict__ W3,
    const float* __restrict__ b3, float* __restrict__ P) {
  __shared__ float pl[256];
  const int b = blockIdx.x, tid = threadIdx.x;
  float m = poolpart[((size_t)b*8)*256 + tid];
#pragma unroll
  for (int s = 1; s < 8; ++s) m = fmaxf(m, poolpart[((size_t)(b*8+s))*256 + tid]);
  pl[tid] = m;
  __syncthreads();
  float acc = b3[tid];
  for (int c = 0; c < 256; ++c) acc = fmaf(pl[c], W3[(size_t)(256 + c)*256 + tid], acc);
  P[(size_t)b*256 + tid] = acc;
}

// ---------- kernel 5 (MFMA): GEMM3 stats pass -> s2sum/s2sq partials ----------
__global__ __launch_bounds__(256) void k_gemm3s_m(
    const u16* __restrict__ hbf, const void* __restrict__ mask, const int* __restrict__ modep,
    const u16* __restrict__ W3t, const float* __restrict__ P,
    float* __restrict__ s2sum, float* __restrict__ s2sq) {
  __shared__ u16 ht[64*264];      // 33.8 KB, [row][k] pitch 264
  __shared__ float mk[64];
  __shared__ float redS[256*4], redQ[256*4];  // [col][quad]
  const int mode = *modep;
  const int tid = threadIdx.x;
  const int rt = blockIdx.x;
  const int row0 = rt*64;
  const int b = rt >> 3;
  if (tid < 64) mk[tid] = read_mask(mask, row0 + tid, mode);
  for (int it = tid; it < 64*32; it += 256) {
    const int row = it >> 5, c8 = it & 31;
    *(uint4*)(ht + row*264 + c8*8) = *(const uint4*)(hbf + (size_t)(row0 + row)*256 + c8*8);
  }
  __syncthreads();
  const int wave = tid >> 6, lane = tid & 63;
  const int lr = lane & 15, lq = lane >> 4;
  f32x4 acc[4][4];
#pragma unroll
  for (int r = 0; r < 4; ++r)
#pragma unroll
    for (int c = 0; c < 4; ++c) acc[r][c] = (f32x4){0.f,0.f,0.f,0.f};
  for (int kc = 0; kc < 256; kc += 32) {
    bf16x8 afr[4];
#pragma unroll
    for (int r = 0; r < 4; ++r)
      afr[r] = *(const bf16x8*)(ht + (r*16 + lr)*264 + kc + lq*8);
#pragma unroll
    for (int c = 0; c < 4; ++c) {
      const bf16x8 bfr = *(const bf16x8*)(W3t + (size_t)(wave*64 + c*16 + lr)*256 + kc + lq*8);
#pragma unroll
      for (int r = 0; r < 4; ++r)
        acc[r][c] = __builtin_amdgcn_mfma_f32_16x16x32_bf16(afr[r], bfr, acc[r][c], 0, 0, 0);
    }
  }
#pragma unroll
  for (int c = 0; c < 4; ++c) {
    const int col = wave*64 + c*16 + lr;
    const float pp = P[(size_t)b*256 + col];
    float sS = 0.f, sQ = 0.f;
#pragma unroll
    for (int r = 0; r < 4; ++r) {
#pragma unroll
      for (int i = 0; i < 4; ++i) {
        const int row = r*16 + lq*4 + i;
        const float v = acc[r][c][i] + pp;
        sS += mk[row]*v; sQ += mk[row]*v*v;
      }
    }
    redS[col*4 + lq] = sS;
    redQ[col*4 + lq] = sQ;
  }
  __syncthreads();
  if (tid < 256) {
    float s = redS[tid*4] + redS[tid*4+1] + redS[tid*4+2] + redS[tid*4+3];
    float q = redQ[tid*4] + redQ[tid*4+1] + redQ[tid*4+2] + redQ[tid*4+3];
    s2sum[(size_t)rt*256 + tid] = s;
    s2sq [(size_t)rt*256 + tid] = q;
  }
}

// ---------- kernel 5b: coalesced slab-reduce of BN2 partials (4096 -> 64) ----------
__global__ __launch_bounds__(256) void k_red2(
    const float* __restrict__ s2sum, const float* __restrict__ s2sq,
    float* __restrict__ mids, float* __restrict__ midq) {
  const int slab = blockIdx.x;  // 0..63
  const int c = threadIdx.x;
  const float* src = blockIdx.y ? s2sq : s2sum;
  float acc = 0.f;
  for (int rt = slab*64; rt < slab*64 + 64; ++rt) acc += src[(size_t)rt*256 + c];
  (blockIdx.y ? midq : mids)[slab*256 + c] = acc;
}

// ---------- kernel 6: finalize BN2 ----------
__global__ __launch_bounds__(256) void k_fin2(
    const float* __restrict__ mids, const float* __restrict__ midq,
    const float* __restrict__ cntf,
    const float* __restrict__ g2, const float* __restrict__ be2,
    float* __restrict__ a2, float* __restrict__ sh2) {
  const int c = threadIdx.x;
  float s = 0.f, q = 0.f;
  for (int k = 0; k < 64; ++k) { s += mids[k*256 + c]; q += midq[k*256 + c]; }
  const float cf = *cntf;
  const float mean = s / cf;
  float var = q / cf - mean*mean; if (var < 0.f) var = 0.f;
  const float a = g2[c] * rsqrtf(var + EPSV);
  a2[c]  = a;
  sh2[c] = be2[c] - mean*a;
}

// ---------- kernel 7 (MFMA): GEMM3 + BN2 + ReLU + GEMM4 + mask -> out col-max partials ----
__global__ __launch_bounds__(256) void k_gemm34_m(
    const u16* __restrict__ hbf, const void* __restrict__ mask, const int* __restrict__ modep,
    const u16* __restrict__ W3t, const float* __restrict__ P,
    const float* __restrict__ a2, const float* __restrict__ sh2,
    const u16* __restrict__ W4t, const float* __restrict__ b4,
    float* __restrict__ outpart) {
  __shared__ u16 ht[64*264];      // h tile, then reused as h2n tile
  __shared__ float mk[64];
  __shared__ float Pl[256], a2l[256], s2l[256];
  __shared__ float redM[128*4];
  const int mode = *modep;
  const int tid = threadIdx.x;
  const int rt = blockIdx.x;
  const int row0 = rt*64;
  const int b = rt >> 3;
  if (tid < 64) mk[tid] = read_mask(mask, row0 + tid, mode);
  Pl[tid] = P[(size_t)b*256 + tid];
  a2l[tid] = a2[tid]; s2l[tid] = sh2[tid];
  for (int it = tid; it < 64*32; it += 256) {
    const int row = it >> 5, c8 = it & 31;
    *(uint4*)(ht + row*264 + c8*8) = *(const uint4*)(hbf + (size_t)(row0 + row)*256 + c8*8);
  }
  __syncthreads();
  const int wave = tid >> 6, lane = tid & 63;
  const int lr = lane & 15, lq = lane >> 4;
  // ---- phase 1: GEMM3 (64x256, K=256) ----
  f32x4 acc[4][4];
#pragma unroll
  for (int r = 0; r < 4; ++r)
#pragma unroll
    for (int c = 0; c < 4; ++c) acc[r][c] = (f32x4){0.f,0.f,0.f,0.f};
  for (int kc = 0; kc < 256; kc += 32) {
    bf16x8 afr[4];
#pragma unroll
    for (int r = 0; r < 4; ++r)
      afr[r] = *(const bf16x8*)(ht + (r*16 + lr)*264 + kc + lq*8);
#pragma unroll
    for (int c = 0; c < 4; ++c) {
      const bf16x8 bfr = *(const bf16x8*)(W3t + (size_t)(wave*64 + c*16 + lr)*256 + kc + lq*8);
#pragma unroll
      for (int r = 0; r < 4; ++r)
        acc[r][c] = __builtin_amdgcn_mfma_f32_16x16x32_bf16(afr[r], bfr, acc[r][c], 0, 0, 0);
    }
  }
  __syncthreads();   // all waves done reading ht
  // BN2 + ReLU -> h2n bf16 into ht (same [row][col] pitch-264 layout)
#pragma unroll
  for (int c = 0; c < 4; ++c) {
    const int col = wave*64 + c*16 + lr;
    const float pp = Pl[col], aa = a2l[col], ss = s2l[col];
#pragma unroll
    for (int r = 0; r < 4; ++r) {
#pragma unroll
      for (int i = 0; i < 4; ++i) {
        const int row = r*16 + lq*4 + i;
        const float z = fmaf(acc[r][c][i] + pp, aa, ss);
        ht[row*264 + col] = f2bf(z > 0.f ? z : 0.f);
      }
    }
  }
  __syncthreads();
  // ---- phase 2: GEMM4 (64x128, K=256). wave w: cols [32w, 32w+32) ----
  f32x4 acc2[4][2];
#pragma unroll
  for (int r = 0; r < 4; ++r)
#pragma unroll
    for (int c = 0; c < 2; ++c) acc2[r][c] = (f32x4){0.f,0.f,0.f,0.f};
  for (int kc = 0; kc < 256; kc += 32) {
    bf16x8 afr[4];
#pragma unroll
    for (int r = 0; r < 4; ++r)
      afr[r] = *(const bf16x8*)(ht + (r*16 + lr)*264 + kc + lq*8);
#pragma unroll
    for (int c = 0; c < 2; ++c) {
      const bf16x8 bfr = *(const bf16x8*)(W4t + (size_t)(wave*32 + c*16 + lr)*256 + kc + lq*8);
#pragma unroll
      for (int r = 0; r < 4; ++r)
        acc2[r][c] = __builtin_amdgcn_mfma_f32_16x16x32_bf16(afr[r], bfr, acc2[r][c], 0, 0, 0);
    }
  }
  // epilogue: +b4, mask, col-max
#pragma unroll
  for (int c = 0; c < 2; ++c) {
    const int col = wave*32 + c*16 + lr;
    const float bb = b4[col];
    float cm = -1e38f;
#pragma unroll
    for (int r = 0; r < 4; ++r) {
#pragma unroll
      for (int i = 0; i < 4; ++i) {
        const int row = r*16 + lq*4 + i;
        cm = fmaxf(cm, (acc2[r][c][i] + bb) * mk[row]);
      }
    }
    redM[col*4 + lq] = cm;
  }
  __syncthreads();
  if (tid < 128) {
    const float m = fmaxf(fmaxf(redM[tid*4], redM[tid*4+1]), fmaxf(redM[tid*4+2], redM[tid*4+3]));
    const int seg = rt & 7;
    outpart[((size_t)(b*8 + seg))*128 + tid] = m;
  }
}

// ---------- kernel 8: reduce 8 segment maxima -> out[b,e] ----------
__global__ __launch_bounds__(256) void k_outred(
    const float* __restrict__ outpart, float* __restrict__ out) {
  const int idx = blockIdx.x*256 + threadIdx.x;  // < 65536
  const int b = idx >> 7, e = idx & 127;
  float m = outpart[((size_t)b*8)*128 + e];
#pragma unroll
  for (int s = 1; s < 8; ++s) m = fmaxf(m, outpart[((size_t)(b*8 + s))*128 + e]);
  out[idx] = m;
}

extern "C" void kernel_launch(void* const* d_in, const int* in_sizes, int n_in,
                              void* d_out, int out_size, void* d_ws, size_t ws_size,
                              hipStream_t stream) {
  const float* x    = (const float*)d_in[0];
  const void*  mask = d_in[1];
  const float* W1   = (const float*)d_in[2];
  const float* b1   = (const float*)d_in[3];
  const float* g1   = (const float*)d_in[4];
  const float* be1  = (const float*)d_in[5];
  const float* W2   = (const float*)d_in[6];
  const float* b2   = (const float*)d_in[7];
  const float* W3   = (const float*)d_in[8];
  const float* b3   = (const float*)d_in[9];
  const float* g2   = (const float*)d_in[10];
  const float* be2  = (const float*)d_in[11];
  const float* W4   = (const float*)d_in[12];
  const float* b4   = (const float*)d_in[13];
  float* out = (float*)d_out;

  char* ws = (char*)d_ws;
  size_t off = 0;
  auto take = [&](size_t bytes) -> char* {
    char* p = ws + off;
    off = (off + bytes + 255) & ~(size_t)255;
    return p;
  };
  u16*   hbf     = (u16*)  take((size_t)MROWS*256*2);   // 128 MiB
  float* s1sum   = (float*)take((size_t)1024*128*4);
  float* s1sq    = (float*)take((size_t)1024*128*4);
  int*   cntpart = (int*)  take((size_t)1024*4);
  float* a1      = (float*)take(128*4);
  float* sh1     = (float*)take(128*4);
  float* cntf    = (float*)take(256);
  float* poolpart= (float*)take((size_t)512*8*256*4);
  float* P       = (float*)take((size_t)512*256*4);
  float* s2sum   = (float*)take((size_t)4096*256*4);
  float* s2sq    = (float*)take((size_t)4096*256*4);
  float* mids    = (float*)take((size_t)64*256*4);
  float* midq    = (float*)take((size_t)64*256*4);
  float* a2      = (float*)take(256*4);
  float* sh2     = (float*)take(256*4);
  float* outpart = (float*)take((size_t)512*8*128*4);
  int*   modep   = (int*)  take(256);
  u16*   w2t     = (u16*)  take((size_t)256*128*2);
  u16*   w3t     = (u16*)  take((size_t)256*256*2);
  u16*   w4t     = (u16*)  take((size_t)128*256*2);

  k_detect<<<1, 256, 0, stream>>>((const unsigned char*)mask, modep);
  k_prep<<<512, 256, 0, stream>>>(W2, W3, W4, w2t, w3t, w4t);
  k_stats1<<<1024, 256, 0, stream>>>(x, mask, W1, b1, modep, s1sum, s1sq, cntpart);
  k_fin1<<<1, 128, 0, stream>>>(s1sum, s1sq, cntpart, g1, be1, a1, sh1, cntf);
  k_gemm2_m<<<RT, 256, 0, stream>>>(x, mask, modep, W1, b1, a1, sh1, w2t, b2, hbf, poolpart);
  k_poolP<<<512, 256, 0, stream>>>(poolpart, W3, b3, P);
  k_gemm3s_m<<<RT, 256, 0, stream>>>(hbf, mask, modep, w3t, P, s2sum, s2sq);
  k_red2<<<dim3(64, 2), 256, 0, stream>>>(s2sum, s2sq, mids, midq);
  k_fin2<<<1, 256, 0, stream>>>(mids, midq, cntf, g2, be2, a2, sh2);
  k_gemm34_m<<<RT, 256, 0, stream>>>(hbf, mask, modep, w3t, P, a2, sh2, w4t, b4, outpart);
  k_outred<<<256, 256, 0, stream>>>(outpart, out);
}

// Round 4
// 356.167 us; speedup vs baseline: 4.5509x; 1.5034x over previous
//
#include <hip/hip_runtime.h>
#include <stdint.h>

#define BB   512
#define NN   512
#define MROWS (BB*NN)      // 262144
#define RT   (MROWS/64)    // 4096 row tiles of 64
#define EPSV 1e-5f

typedef unsigned short u16;
typedef __attribute__((ext_vector_type(8))) short bf16x8;
typedef __attribute__((ext_vector_type(4))) float f32x4;

// ---------- helpers ----------
__device__ __forceinline__ float read_mask(const void* mp, int r, int mode) {
  if (mode == 0) return ((const unsigned char*)mp)[r] ? 1.f : 0.f;
  if (mode == 1) return ((const unsigned int*)mp)[r] ? 1.f : 0.f;
  return ((const unsigned long long*)mp)[r] ? 1.f : 0.f;
}

__device__ __forceinline__ u16 f2bf(float f) {
  union { float f; unsigned int u; } v; v.f = f;
  unsigned int u = v.u;
  return (u16)((u + 0x7FFFu + ((u >> 16) & 1u)) >> 16);
}

__device__ __forceinline__ float bf2f(u16 b) {
  union { unsigned int u; float f; } t;
  t.u = ((unsigned int)b) << 16;
  return t.f;
}

// ---------- kernel 0: detect mask element layout ----------
__global__ void k_detect(const unsigned char* __restrict__ mu, int* __restrict__ mode) {
  __shared__ int c1, c4;
  if (threadIdx.x == 0) { c1 = 0; c4 = 0; }
  __syncthreads();
  for (int i = threadIdx.x; i < 4096; i += 256) {
    const unsigned char b = mu[i];
    if (b) {
      if ((i & 3) == 1) atomicAdd(&c1, 1);
      if ((i & 7) == 4) atomicAdd(&c4, 1);
    }
  }
  __syncthreads();
  if (threadIdx.x == 0) *mode = c1 ? 0 : (c4 ? 1 : 2);
}

// ---------- weight prep: bf16 transposed Wt[n][k] ----------
__global__ __launch_bounds__(256) void k_prep(
    const float* __restrict__ W2, const float* __restrict__ W3, const float* __restrict__ W4,
    u16* __restrict__ w2t, u16* __restrict__ w3t, u16* __restrict__ w4t) {
  const int idx = blockIdx.x*256 + threadIdx.x;  // < 131072
  if (idx < 32768) {                 // W2t [256 n][128 k]
    const int n = idx >> 7, k = idx & 127;
    w2t[idx] = f2bf(W2[(size_t)k*256 + n]);
  } else if (idx < 98304) {          // W3t [256 n][256 k] (rows 0..256 of W3)
    const int j = idx - 32768;
    const int n = j >> 8, k = j & 255;
    w3t[j] = f2bf(W3[(size_t)k*256 + n]);
  } else {                           // W4t [128 n][256 k]
    const int j = idx - 98304;
    const int n = j >> 8, k = j & 255;
    w4t[j] = f2bf(W4[(size_t)k*128 + n]);
  }
}

// ---------- kernel 1: BN1 partial stats (grid 2048, 128 rows/blk) ----------
__global__ __launch_bounds__(256) void k_stats1(
    const float* __restrict__ x, const void* __restrict__ mask,
    const float* __restrict__ W1, const float* __restrict__ b1,
    const int* __restrict__ modep,
    float* __restrict__ s1sum, float* __restrict__ s1sq, int* __restrict__ cntpart) {
  const int mode = *modep;
  const int tid  = threadIdx.x;
  const int c    = tid & 127;
  const int half = tid >> 7;
  const int blk  = blockIdx.x;
  float w[6];
#pragma unroll
  for (int k = 0; k < 6; ++k) w[k] = W1[k*128 + c];
  const float bb = b1[c];
  float accS = 0.f, accQ = 0.f; int cnt = 0;
  for (int i = half; i < 128; i += 2) {
    const int r = blk*128 + i;
    const float mv = read_mask(mask, r, mode);
    const float* xr = x + (size_t)r*6;
    float h = bb;
#pragma unroll
    for (int k = 0; k < 6; ++k) h = fmaf(xr[k], w[k], h);
    accS += mv*h; accQ += mv*h*h;
    if (c == 0) cnt += (mv != 0.f);
  }
  __shared__ float rs[256], rq[256];
  __shared__ int rc[2];
  rs[tid] = accS; rq[tid] = accQ;
  if (c == 0) rc[half] = cnt;
  __syncthreads();
  if (tid < 128) {
    s1sum[(size_t)blk*128 + tid] = rs[tid] + rs[tid+128];
    s1sq [(size_t)blk*128 + tid] = rq[tid] + rq[tid+128];
    if (tid == 0) cntpart[blk] = rc[0] + rc[1];
  }
}

// ---------- kernel 1b: slab-reduce s1 partials 2048 -> 16 ----------
__global__ __launch_bounds__(256) void k_red1(
    const float* __restrict__ s1sum, const float* __restrict__ s1sq,
    float* __restrict__ mid1s, float* __restrict__ mid1q) {
  const int blk = blockIdx.x;  // 0..15
  const int c = threadIdx.x & 127, g = threadIdx.x >> 7;
  float s = 0.f, q = 0.f;
  for (int r = blk*128 + g*64; r < blk*128 + g*64 + 64; ++r) {
    s += s1sum[(size_t)r*128 + c];
    q += s1sq [(size_t)r*128 + c];
  }
  __shared__ float rs[256], rq[256];
  rs[threadIdx.x] = s; rq[threadIdx.x] = q;
  __syncthreads();
  if (threadIdx.x < 128) {
    mid1s[blk*128 + c] = rs[c] + rs[c+128];
    mid1q[blk*128 + c] = rq[c] + rq[c+128];
  }
}

// ---------- kernel 2: finalize BN1 -> folded W1p = W1*a1, c1p = b1*a1 + sh1 ----------
__global__ __launch_bounds__(128) void k_fin1(
    const float* __restrict__ mid1s, const float* __restrict__ mid1q,
    const int* __restrict__ cntpart,
    const float* __restrict__ W1, const float* __restrict__ b1,
    const float* __restrict__ g1, const float* __restrict__ be1,
    float* __restrict__ w1p, float* __restrict__ c1p, float* __restrict__ cntf) {
  const int c = threadIdx.x;
  float s = 0.f, q = 0.f;
#pragma unroll
  for (int b = 0; b < 16; ++b) { s += mid1s[b*128 + c]; q += mid1q[b*128 + c]; }
  __shared__ int cl[128];
  int cn = 0;
  for (int b = c*16; b < c*16 + 16; ++b) cn += cntpart[b];
  cl[c] = cn;
  __syncthreads();
  __shared__ float cshare;
  if (c == 0) {
    int t = 0;
    for (int i = 0; i < 128; ++i) t += cl[i];
    float cf = (float)t; if (cf < 1.f) cf = 1.f;
    cshare = cf; *cntf = cf;
  }
  __syncthreads();
  const float cf = cshare;
  const float mean = s / cf;
  float var = q / cf - mean*mean; if (var < 0.f) var = 0.f;
  const float a = g1[c] * rsqrtf(var + EPSV);
  const float sh = be1[c] - mean*a;
  c1p[c] = fmaf(b1[c], a, sh);
#pragma unroll
  for (int k = 0; k < 6; ++k) w1p[k*128 + c] = W1[k*128 + c] * a;
}

// ---------- MEGA kernel: GEMM1+BN1+ReLU+GEMM2+mask -> pool partials,
//            then GEMM3a (h@W3[0:256]) -> acc3 bf16 + BN2 stat partials ----------
__global__ __launch_bounds__(256) void k_mega(
    const float* __restrict__ x, const void* __restrict__ mask, const int* __restrict__ modep,
    const float* __restrict__ w1p, const float* __restrict__ c1p,
    const u16* __restrict__ W2t, const float* __restrict__ b2,
    const u16* __restrict__ W3t,
    u16* __restrict__ acc3buf, float* __restrict__ poolpart,
    float* __restrict__ s2sum, float* __restrict__ s2sq) {
  __shared__ u16 h1[64*136];     // 17408 B  [row][k] pitch 136
  __shared__ u16 outt[64*264];   // 33792 B  [row][col] pitch 264 (h, then acc3)
  __shared__ float xs[384];
  __shared__ float W1l[768];
  __shared__ float c1l[128];
  __shared__ float mk[64];
  const int mode = *modep;
  const int tid = threadIdx.x;
  const int rt = blockIdx.x;
  const int row0 = rt*64;
  const int b = rt >> 3, seg = rt & 7;
  // stage x rows, folded W1, mask
  for (int i = tid; i < 384; i += 256) xs[i] = x[(size_t)row0*6 + i];
  for (int i = tid; i < 768; i += 256) W1l[i] = w1p[i];
  if (tid < 128) c1l[tid] = c1p[tid];
  if (tid < 64) mk[tid] = read_mask(mask, row0 + tid, mode);
  __syncthreads();
  // phase 1: h1n = relu(x@W1' + c1') bf16 into LDS
  {
    const int rl = tid & 63;
    const int c0 = (tid >> 6) * 32;
    float xv[6];
#pragma unroll
    for (int k = 0; k < 6; ++k) xv[k] = xs[rl*6 + k];
#pragma unroll 4
    for (int c = c0; c < c0+32; ++c) {
      float h = c1l[c];
#pragma unroll
      for (int k = 0; k < 6; ++k) h = fmaf(xv[k], W1l[k*128 + c], h);
      h1[rl*136 + c] = f2bf(h > 0.f ? h : 0.f);
    }
  }
  __syncthreads();
  const int wave = tid >> 6, lane = tid & 63;
  const int lr = lane & 15, lq = lane >> 4;
  // phase 2: GEMM2 (64 x 256, K=128); wave w: cols [64w, 64w+64)
  {
    f32x4 acc[4][4];
#pragma unroll
    for (int r = 0; r < 4; ++r)
#pragma unroll
      for (int c = 0; c < 4; ++c) acc[r][c] = (f32x4){0.f,0.f,0.f,0.f};
#pragma unroll
    for (int kc = 0; kc < 128; kc += 32) {
      bf16x8 afr[4];
#pragma unroll
      for (int r = 0; r < 4; ++r)
        afr[r] = *(const bf16x8*)(h1 + (r*16 + lr)*136 + kc + lq*8);
#pragma unroll
      for (int c = 0; c < 4; ++c) {
        const bf16x8 bfr = *(const bf16x8*)(W2t + (size_t)(wave*64 + c*16 + lr)*128 + kc + lq*8);
#pragma unroll
        for (int r = 0; r < 4; ++r)
          acc[r][c] = __builtin_amdgcn_mfma_f32_16x16x32_bf16(afr[r], bfr, acc[r][c], 0, 0, 0);
      }
    }
    // epilogue: h = (acc+b2)*mask -> outt (bf16) + pool col-max via shfl
#pragma unroll
    for (int c = 0; c < 4; ++c) {
      const int col = wave*64 + c*16 + lr;
      const float bb = b2[col];
      float cm = -1e38f;
#pragma unroll
      for (int r = 0; r < 4; ++r) {
#pragma unroll
        for (int i = 0; i < 4; ++i) {
          const int row = r*16 + lq*4 + i;
          const float v = (acc[r][c][i] + bb) * mk[row];
          outt[row*264 + col] = f2bf(v);
          cm = fmaxf(cm, v);
        }
      }
      cm = fmaxf(cm, __shfl_xor(cm, 16, 64));
      cm = fmaxf(cm, __shfl_xor(cm, 32, 64));
      if (lq == 0) poolpart[((size_t)(b*8 + seg))*256 + col] = cm;
    }
  }
  __syncthreads();
  // phase 3: GEMM3a (64 x 256, K=256) from outt; acc3 = h@W3a
  f32x4 acc3[4][4];
#pragma unroll
  for (int r = 0; r < 4; ++r)
#pragma unroll
    for (int c = 0; c < 4; ++c) acc3[r][c] = (f32x4){0.f,0.f,0.f,0.f};
#pragma unroll 2
  for (int kc = 0; kc < 256; kc += 32) {
    bf16x8 afr[4];
#pragma unroll
    for (int r = 0; r < 4; ++r)
      afr[r] = *(const bf16x8*)(outt + (r*16 + lr)*264 + kc + lq*8);
#pragma unroll
    for (int c = 0; c < 4; ++c) {
      const bf16x8 bfr = *(const bf16x8*)(W3t + (size_t)(wave*64 + c*16 + lr)*256 + kc + lq*8);
#pragma unroll
      for (int r = 0; r < 4; ++r)
        acc3[r][c] = __builtin_amdgcn_mfma_f32_16x16x32_bf16(afr[r], bfr, acc3[r][c], 0, 0, 0);
    }
  }
  __syncthreads();   // all waves done reading outt
  // epilogue: round acc3->bf16, stats partials on rounded values, write outt
#pragma unroll
  for (int c = 0; c < 4; ++c) {
    const int col = wave*64 + c*16 + lr;
    float sS = 0.f, sQ = 0.f;
#pragma unroll
    for (int r = 0; r < 4; ++r) {
#pragma unroll
      for (int i = 0; i < 4; ++i) {
        const int row = r*16 + lq*4 + i;
        const u16 w16 = f2bf(acc3[r][c][i]);
        const float w = bf2f(w16);
        outt[row*264 + col] = w16;
        sS += mk[row]*w;
        sQ += mk[row]*w*w;
      }
    }
    sS += __shfl_xor(sS, 16, 64);
    sS += __shfl_xor(sS, 32, 64);
    sQ += __shfl_xor(sQ, 16, 64);
    sQ += __shfl_xor(sQ, 32, 64);
    if (lq == 0) {
      s2sum[(size_t)rt*256 + col] = sS;
      s2sq [(size_t)rt*256 + col] = sQ;
    }
  }
  __syncthreads();
  // coalesced store acc3 tile -> global
  for (int it = tid; it < 64*32; it += 256) {
    const int row = it >> 5, c8 = it & 31;
    *(uint4*)(acc3buf + (size_t)(row0 + row)*256 + c8*8) = *(const uint4*)(outt + row*264 + c8*8);
  }
}

// ---------- pool reduce + P[b,:] = pooled[b]@W3[256:512] + b3 ----------
__global__ __launch_bounds__(256) void k_poolP(
    const float* __restrict__ poolpart, const float* __restrict__ W3,
    const float* __restrict__ b3, float* __restrict__ P) {
  __shared__ float pl[256];
  const int b = blockIdx.x, tid = threadIdx.x;
  float m = poolpart[((size_t)b*8)*256 + tid];
#pragma unroll
  for (int s = 1; s < 8; ++s) m = fmaxf(m, poolpart[((size_t)(b*8+s))*256 + tid]);
  pl[tid] = m;
  __syncthreads();
  float acc = b3[tid];
  for (int c = 0; c < 256; ++c) acc = fmaf(pl[c], W3[(size_t)(256 + c)*256 + tid], acc);
  P[(size_t)b*256 + tid] = acc;
}

// ---------- fold P into BN2 partials per batch: outS = S + cnt*P, outQ = Q + 2PS + cnt*P^2 ----------
__global__ __launch_bounds__(256) void k_red2b(
    const float* __restrict__ s2sum, const float* __restrict__ s2sq,
    const int* __restrict__ cntpart, const float* __restrict__ P,
    float* __restrict__ outS, float* __restrict__ outQ) {
  const int b = blockIdx.x;   // 0..511
  const int c = threadIdx.x;
  __shared__ float cntb;
  if (c == 0)  // batch b = stats1 blocks 4b..4b+3 (128 rows each)
    cntb = (float)(cntpart[4*b] + cntpart[4*b+1] + cntpart[4*b+2] + cntpart[4*b+3]);
  float S = 0.f, Q = 0.f;
#pragma unroll
  for (int s = 0; s < 8; ++s) {
    S += s2sum[(size_t)(b*8 + s)*256 + c];
    Q += s2sq [(size_t)(b*8 + s)*256 + c];
  }
  __syncthreads();
  const float p = P[(size_t)b*256 + c];
  outS[(size_t)b*256 + c] = fmaf(cntb, p, S);
  outQ[(size_t)b*256 + c] = fmaf(cntb, p*p, fmaf(2.f*p, S, Q));
}

// ---------- reduce 512 -> 32 ----------
__global__ __launch_bounds__(256) void k_red2c(
    const float* __restrict__ outS, const float* __restrict__ outQ,
    float* __restrict__ midS, float* __restrict__ midQ) {
  const int slab = blockIdx.x;  // 0..31
  const int c = threadIdx.x;
  const float* src = blockIdx.y ? outQ : outS;
  float acc = 0.f;
  for (int b = slab*16; b < slab*16 + 16; ++b) acc += src[(size_t)b*256 + c];
  (blockIdx.y ? midQ : midS)[slab*256 + c] = acc;
}

// ---------- finalize BN2 ----------
__global__ __launch_bounds__(256) void k_fin2(
    const float* __restrict__ midS, const float* __restrict__ midQ,
    const float* __restrict__ cntf,
    const float* __restrict__ g2, const float* __restrict__ be2,
    float* __restrict__ a2, float* __restrict__ sh2) {
  const int c = threadIdx.x;
  float s = 0.f, q = 0.f;
#pragma unroll
  for (int k = 0; k < 32; ++k) { s += midS[k*256 + c]; q += midQ[k*256 + c]; }
  const float cf = *cntf;
  const float mean = s / cf;
  float var = q / cf - mean*mean; if (var < 0.f) var = 0.f;
  const float a = g2[c] * rsqrtf(var + EPSV);
  a2[c]  = a;
  sh2[c] = be2[c] - mean*a;
}

// ---------- GEMM4: z = relu((acc3+P)*a2+sh2); out-col-max of z@W4 + b4, masked ----------
__global__ __launch_bounds__(256) void k_gemm4(
    const u16* __restrict__ acc3buf, const void* __restrict__ mask, const int* __restrict__ modep,
    const float* __restrict__ P, const float* __restrict__ a2, const float* __restrict__ sh2,
    const u16* __restrict__ W4t, const float* __restrict__ b4,
    float* __restrict__ outpart) {
  __shared__ u16 a2t[64*264];   // 33792 B  [row][k] pitch 264
  __shared__ float a2l[256], s2b[256];
  __shared__ float mk[64];
  const int mode = *modep;
  const int tid = threadIdx.x;
  const int rt = blockIdx.x;
  const int row0 = rt*64;
  const int b = rt >> 3, seg = rt & 7;
  if (tid < 64) mk[tid] = read_mask(mask, row0 + tid, mode);
  {  // fold P into shift: z = v*a2 + (P*a2 + sh2)
    const float aa = a2[tid];
    a2l[tid] = aa;
    s2b[tid] = fmaf(P[(size_t)b*256 + tid], aa, sh2[tid]);
  }
  __syncthreads();
  // stage + BN2 + ReLU -> a2t
  for (int it = tid; it < 64*32; it += 256) {
    const int row = it >> 5, c8 = it & 31;
    const uint4 u = *(const uint4*)(acc3buf + (size_t)(row0 + row)*256 + c8*8);
    const u16* us = (const u16*)&u;
    u16 z8[8];
#pragma unroll
    for (int j = 0; j < 8; ++j) {
      const int cc = c8*8 + j;
      const float z = fmaf(bf2f(us[j]), a2l[cc], s2b[cc]);
      z8[j] = f2bf(z > 0.f ? z : 0.f);
    }
    *(uint4*)(a2t + row*264 + c8*8) = *(const uint4*)z8;
  }
  __syncthreads();
  const int wave = tid >> 6, lane = tid & 63;
  const int lr = lane & 15, lq = lane >> 4;
  // GEMM4 (64 x 128, K=256); wave w: cols [32w, 32w+32)
  f32x4 acc2[4][2];
#pragma unroll
  for (int r = 0; r < 4; ++r)
#pragma unroll
    for (int c = 0; c < 2; ++c) acc2[r][c] = (f32x4){0.f,0.f,0.f,0.f};
#pragma unroll 2
  for (int kc = 0; kc < 256; kc += 32) {
    bf16x8 afr[4];
#pragma unroll
    for (int r = 0; r < 4; ++r)
      afr[r] = *(const bf16x8*)(a2t + (r*16 + lr)*264 + kc + lq*8);
#pragma unroll
    for (int c = 0; c < 2; ++c) {
      const bf16x8 bfr = *(const bf16x8*)(W4t + (size_t)(wave*32 + c*16 + lr)*256 + kc + lq*8);
#pragma unroll
      for (int r = 0; r < 4; ++r)
        acc2[r][c] = __builtin_amdgcn_mfma_f32_16x16x32_bf16(afr[r], bfr, acc2[r][c], 0, 0, 0);
    }
  }
#pragma unroll
  for (int c = 0; c < 2; ++c) {
    const int col = wave*32 + c*16 + lr;
    const float bb = b4[col];
    float cm = -1e38f;
#pragma unroll
    for (int r = 0; r < 4; ++r) {
#pragma unroll
      for (int i = 0; i < 4; ++i) {
        const int row = r*16 + lq*4 + i;
        cm = fmaxf(cm, (acc2[r][c][i] + bb) * mk[row]);
      }
    }
    cm = fmaxf(cm, __shfl_xor(cm, 16, 64));
    cm = fmaxf(cm, __shfl_xor(cm, 32, 64));
    if (lq == 0) outpart[((size_t)(b*8 + seg))*128 + col] = cm;
  }
}

// ---------- reduce 8 segment maxima -> out[b,e] ----------
__global__ __launch_bounds__(256) void k_outred(
    const float* __restrict__ outpart, float* __restrict__ out) {
  const int idx = blockIdx.x*256 + threadIdx.x;  // < 65536
  const int b = idx >> 7, e = idx & 127;
  float m = outpart[((size_t)b*8)*128 + e];
#pragma unroll
  for (int s = 1; s < 8; ++s) m = fmaxf(m, outpart[((size_t)(b*8 + s))*128 + e]);
  out[idx] = m;
}

extern "C" void kernel_launch(void* const* d_in, const int* in_sizes, int n_in,
                              void* d_out, int out_size, void* d_ws, size_t ws_size,
                              hipStream_t stream) {
  const float* x    = (const float*)d_in[0];
  const void*  mask = d_in[1];
  const float* W1   = (const float*)d_in[2];
  const float* b1   = (const float*)d_in[3];
  const float* g1   = (const float*)d_in[4];
  const float* be1  = (const float*)d_in[5];
  const float* W2   = (const float*)d_in[6];
  const float* b2   = (const float*)d_in[7];
  const float* W3   = (const float*)d_in[8];
  const float* b3   = (const float*)d_in[9];
  const float* g2   = (const float*)d_in[10];
  const float* be2  = (const float*)d_in[11];
  const float* W4   = (const float*)d_in[12];
  const float* b4   = (const float*)d_in[13];
  float* out = (float*)d_out;

  char* ws = (char*)d_ws;
  size_t off = 0;
  auto take = [&](size_t bytes) -> char* {
    char* p = ws + off;
    off = (off + bytes + 255) & ~(size_t)255;
    return p;
  };
  u16*   acc3buf = (u16*)  take((size_t)MROWS*256*2);   // 128 MiB
  float* s1sum   = (float*)take((size_t)2048*128*4);
  float* s1sq    = (float*)take((size_t)2048*128*4);
  int*   cntpart = (int*)  take((size_t)2048*4);
  float* mid1s   = (float*)take((size_t)16*128*4);
  float* mid1q   = (float*)take((size_t)16*128*4);
  float* w1p     = (float*)take(768*4);
  float* c1p     = (float*)take(128*4);
  float* cntf    = (float*)take(256);
  float* poolpart= (float*)take((size_t)512*8*256*4);
  float* P       = (float*)take((size_t)512*256*4);
  float* s2sum   = (float*)take((size_t)4096*256*4);
  float* s2sq    = (float*)take((size_t)4096*256*4);
  float* outS    = (float*)take((size_t)512*256*4);
  float* outQ    = (float*)take((size_t)512*256*4);
  float* midS    = (float*)take((size_t)32*256*4);
  float* midQ    = (float*)take((size_t)32*256*4);
  float* a2      = (float*)take(256*4);
  float* sh2     = (float*)take(256*4);
  float* outpart = (float*)take((size_t)512*8*128*4);
  int*   modep   = (int*)  take(256);
  u16*   w2t     = (u16*)  take((size_t)256*128*2);
  u16*   w3t     = (u16*)  take((size_t)256*256*2);
  u16*   w4t     = (u16*)  take((size_t)128*256*2);

  k_detect<<<1, 256, 0, stream>>>((const unsigned char*)mask, modep);
  k_prep<<<512, 256, 0, stream>>>(W2, W3, W4, w2t, w3t, w4t);
  k_stats1<<<2048, 256, 0, stream>>>(x, mask, W1, b1, modep, s1sum, s1sq, cntpart);
  k_red1<<<16, 256, 0, stream>>>(s1sum, s1sq, mid1s, mid1q);
  k_fin1<<<1, 128, 0, stream>>>(mid1s, mid1q, cntpart, W1, b1, g1, be1, w1p, c1p, cntf);
  k_mega<<<RT, 256, 0, stream>>>(x, mask, modep, w1p, c1p, w2t, b2, w3t,
                                 acc3buf, poolpart, s2sum, s2sq);
  k_poolP<<<512, 256, 0, stream>>>(poolpart, W3, b3, P);
  k_red2b<<<512, 256, 0, stream>>>(s2sum, s2sq, cntpart, P, outS, outQ);
  k_red2c<<<dim3(32, 2), 256, 0, stream>>>(outS, outQ, midS, midQ);
  k_fin2<<<1, 256, 0, stream>>>(midS, midQ, cntf, g2, be2, a2, sh2);
  k_gemm4<<<RT, 256, 0, stream>>>(acc3buf, mask, modep, P, a2, sh2, w4t, b4, outpart);
  k_outred<<<256, 256, 0, stream>>>(outpart, out);
}

// Round 5
// 337.402 us; speedup vs baseline: 4.8040x; 1.0556x over previous
//
#include <hip/hip_runtime.h>
#include <stdint.h>

#define BB   512
#define NN   512
#define MROWS (BB*NN)      // 262144
#define RT   (MROWS/64)    // 4096 row tiles of 64
#define EPSV 1e-5f

typedef unsigned short u16;
typedef __attribute__((ext_vector_type(8))) short bf16x8;
typedef __attribute__((ext_vector_type(4))) float f32x4;

// ---------- helpers ----------
__device__ __forceinline__ float read_mask(const void* mp, int r, int mode) {
  if (mode == 0) return ((const unsigned char*)mp)[r] ? 1.f : 0.f;
  if (mode == 1) return ((const unsigned int*)mp)[r] ? 1.f : 0.f;
  return ((const unsigned long long*)mp)[r] ? 1.f : 0.f;
}

__device__ __forceinline__ u16 f2bf(float f) {
  union { float f; unsigned int u; } v; v.f = f;
  unsigned int u = v.u;
  return (u16)((u + 0x7FFFu + ((u >> 16) & 1u)) >> 16);
}

__device__ __forceinline__ float bf2f(u16 b) {
  union { unsigned int u; float f; } t;
  t.u = ((unsigned int)b) << 16;
  return t.f;
}

// ---------- kernel 0: detect mask element layout ----------
__global__ void k_detect(const unsigned char* __restrict__ mu, int* __restrict__ mode) {
  __shared__ int c1, c4;
  if (threadIdx.x == 0) { c1 = 0; c4 = 0; }
  __syncthreads();
  for (int i = threadIdx.x; i < 4096; i += 256) {
    const unsigned char b = mu[i];
    if (b) {
      if ((i & 3) == 1) atomicAdd(&c1, 1);
      if ((i & 7) == 4) atomicAdd(&c4, 1);
    }
  }
  __syncthreads();
  if (threadIdx.x == 0) *mode = c1 ? 0 : (c4 ? 1 : 2);
}

// ---------- weight prep: bf16 transposed Wt[n][k] ----------
__global__ __launch_bounds__(256) void k_prep(
    const float* __restrict__ W2, const float* __restrict__ W3, const float* __restrict__ W4,
    u16* __restrict__ w2t, u16* __restrict__ w3t, u16* __restrict__ w4t) {
  const int idx = blockIdx.x*256 + threadIdx.x;  // < 131072
  if (idx < 32768) {                 // W2t [256 n][128 k]
    const int n = idx >> 7, k = idx & 127;
    w2t[idx] = f2bf(W2[(size_t)k*256 + n]);
  } else if (idx < 98304) {          // W3t [256 n][256 k] (rows 0..256 of W3)
    const int j = idx - 32768;
    const int n = j >> 8, k = j & 255;
    w3t[j] = f2bf(W3[(size_t)k*256 + n]);
  } else {                           // W4t [128 n][256 k]
    const int j = idx - 98304;
    const int n = j >> 8, k = j & 255;
    w4t[j] = f2bf(W4[(size_t)k*128 + n]);
  }
}

// ---------- kernel 1: BN1 partial stats (grid 2048, 128 rows/blk) ----------
__global__ __launch_bounds__(256) void k_stats1(
    const float* __restrict__ x, const void* __restrict__ mask,
    const float* __restrict__ W1, const float* __restrict__ b1,
    const int* __restrict__ modep,
    float* __restrict__ s1sum, float* __restrict__ s1sq, int* __restrict__ cntpart) {
  const int mode = *modep;
  const int tid  = threadIdx.x;
  const int c    = tid & 127;
  const int half = tid >> 7;
  const int blk  = blockIdx.x;
  float w[6];
#pragma unroll
  for (int k = 0; k < 6; ++k) w[k] = W1[k*128 + c];
  const float bb = b1[c];
  float accS = 0.f, accQ = 0.f; int cnt = 0;
  for (int i = half; i < 128; i += 2) {
    const int r = blk*128 + i;
    const float mv = read_mask(mask, r, mode);
    const float* xr = x + (size_t)r*6;
    float h = bb;
#pragma unroll
    for (int k = 0; k < 6; ++k) h = fmaf(xr[k], w[k], h);
    accS += mv*h; accQ += mv*h*h;
    if (c == 0) cnt += (mv != 0.f);
  }
  __shared__ float rs[256], rq[256];
  __shared__ int rc[2];
  rs[tid] = accS; rq[tid] = accQ;
  if (c == 0) rc[half] = cnt;
  __syncthreads();
  if (tid < 128) {
    s1sum[(size_t)blk*128 + tid] = rs[tid] + rs[tid+128];
    s1sq [(size_t)blk*128 + tid] = rq[tid] + rq[tid+128];
    if (tid == 0) cntpart[blk] = rc[0] + rc[1];
  }
}

// ---------- kernel 1b: slab-reduce s1 partials 2048 -> 16 ----------
__global__ __launch_bounds__(256) void k_red1(
    const float* __restrict__ s1sum, const float* __restrict__ s1sq,
    float* __restrict__ mid1s, float* __restrict__ mid1q) {
  const int blk = blockIdx.x;  // 0..15
  const int c = threadIdx.x & 127, g = threadIdx.x >> 7;
  float s = 0.f, q = 0.f;
  for (int r = blk*128 + g*64; r < blk*128 + g*64 + 64; ++r) {
    s += s1sum[(size_t)r*128 + c];
    q += s1sq [(size_t)r*128 + c];
  }
  __shared__ float rs[256], rq[256];
  rs[threadIdx.x] = s; rq[threadIdx.x] = q;
  __syncthreads();
  if (threadIdx.x < 128) {
    mid1s[blk*128 + c] = rs[c] + rs[c+128];
    mid1q[blk*128 + c] = rq[c] + rq[c+128];
  }
}

// ---------- kernel 2: finalize BN1 -> folded W1p = W1*a1, c1p = b1*a1 + sh1 ----------
__global__ __launch_bounds__(128) void k_fin1(
    const float* __restrict__ mid1s, const float* __restrict__ mid1q,
    const int* __restrict__ cntpart,
    const float* __restrict__ W1, const float* __restrict__ b1,
    const float* __restrict__ g1, const float* __restrict__ be1,
    float* __restrict__ w1p, float* __restrict__ c1p, float* __restrict__ cntf) {
  const int c = threadIdx.x;
  float s = 0.f, q = 0.f;
#pragma unroll
  for (int b = 0; b < 16; ++b) { s += mid1s[b*128 + c]; q += mid1q[b*128 + c]; }
  __shared__ int cl[128];
  int cn = 0;
  for (int b = c*16; b < c*16 + 16; ++b) cn += cntpart[b];
  cl[c] = cn;
  __syncthreads();
  __shared__ float cshare;
  if (c == 0) {
    int t = 0;
    for (int i = 0; i < 128; ++i) t += cl[i];
    float cf = (float)t; if (cf < 1.f) cf = 1.f;
    cshare = cf; *cntf = cf;
  }
  __syncthreads();
  const float cf = cshare;
  const float mean = s / cf;
  float var = q / cf - mean*mean; if (var < 0.f) var = 0.f;
  const float a = g1[c] * rsqrtf(var + EPSV);
  const float sh = be1[c] - mean*a;
  c1p[c] = fmaf(b1[c], a, sh);
#pragma unroll
  for (int k = 0; k < 6; ++k) w1p[k*128 + c] = W1[k*128 + c] * a;
}

// ---------- MEGA kernel: GEMM1+BN1+ReLU+GEMM2+mask -> pool partials,
//            then GEMM3a (h@W3[0:256]) -> acc3 bf16 + BN2 stat partials ----------
// LDS: 17408 + 33792 + 1536 + 256 = 52992 B -> 3 blocks/CU
__global__ __launch_bounds__(256, 3) void k_mega(
    const float* __restrict__ x, const void* __restrict__ mask, const int* __restrict__ modep,
    const float* __restrict__ w1p, const float* __restrict__ c1p,
    const u16* __restrict__ W2t, const float* __restrict__ b2,
    const u16* __restrict__ W3t,
    u16* __restrict__ acc3buf, float* __restrict__ poolpart,
    float* __restrict__ s2sum, float* __restrict__ s2sq) {
  __shared__ u16 hA[64*136];     // 17408 B  [row][k] pitch 136
  __shared__ u16 outt[64*264];   // 33792 B  [row][col] pitch 264 (h, then acc3)
  __shared__ float xs[384];
  __shared__ float mk[64];
  const int mode = *modep;
  const int tid = threadIdx.x;
  const int rt = blockIdx.x;
  const int row0 = rt*64;
  const int b = rt >> 3, seg = rt & 7;
  // stage x rows + mask
  for (int i = tid; i < 384; i += 256) xs[i] = x[(size_t)row0*6 + i];
  if (tid < 64) mk[tid] = read_mask(mask, row0 + tid, mode);
  __syncthreads();
  // phase 1: h1n = relu(x@W1' + c1') bf16 into hA.
  // thread: 4 cols (coalesced float4 weight loads) x 8 rows.
  {
    const int c0 = (tid & 31) * 4;
    const int r0 = (tid >> 5) * 8;
    float4 wv[6];
#pragma unroll
    for (int k = 0; k < 6; ++k) wv[k] = *(const float4*)(w1p + k*128 + c0);
    const float4 cc = *(const float4*)(c1p + c0);
#pragma unroll
    for (int r = 0; r < 8; ++r) {
      const int row = r0 + r;
      float xv[6];
#pragma unroll
      for (int k = 0; k < 6; ++k) xv[k] = xs[row*6 + k];
      float v0 = cc.x, v1 = cc.y, v2 = cc.z, v3 = cc.w;
#pragma unroll
      for (int k = 0; k < 6; ++k) {
        v0 = fmaf(xv[k], wv[k].x, v0);
        v1 = fmaf(xv[k], wv[k].y, v1);
        v2 = fmaf(xv[k], wv[k].z, v2);
        v3 = fmaf(xv[k], wv[k].w, v3);
      }
      ushort4 z;
      z.x = f2bf(v0 > 0.f ? v0 : 0.f);
      z.y = f2bf(v1 > 0.f ? v1 : 0.f);
      z.z = f2bf(v2 > 0.f ? v2 : 0.f);
      z.w = f2bf(v3 > 0.f ? v3 : 0.f);
      *(ushort4*)(hA + row*136 + c0) = z;
    }
  }
  __syncthreads();
  const int wave = tid >> 6, lane = tid & 63;
  const int lr = lane & 15, lq = lane >> 4;
  // phase 2: GEMM2 (64 x 256, K=128); wave w: cols [64w, 64w+64)
  {
    f32x4 acc[4][4];
#pragma unroll
    for (int r = 0; r < 4; ++r)
#pragma unroll
      for (int c = 0; c < 4; ++c) acc[r][c] = (f32x4){0.f,0.f,0.f,0.f};
#pragma unroll
    for (int kc = 0; kc < 128; kc += 32) {
      bf16x8 afr[4];
#pragma unroll
      for (int r = 0; r < 4; ++r)
        afr[r] = *(const bf16x8*)(hA + (r*16 + lr)*136 + kc + lq*8);
#pragma unroll
      for (int c = 0; c < 4; ++c) {
        const bf16x8 bfr = *(const bf16x8*)(W2t + (size_t)(wave*64 + c*16 + lr)*128 + kc + lq*8);
#pragma unroll
        for (int r = 0; r < 4; ++r)
          acc[r][c] = __builtin_amdgcn_mfma_f32_16x16x32_bf16(afr[r], bfr, acc[r][c], 0, 0, 0);
      }
    }
    // epilogue: h = (acc+b2)*mask -> outt (bf16) + pool col-max via shfl
#pragma unroll
    for (int c = 0; c < 4; ++c) {
      const int col = wave*64 + c*16 + lr;
      const float bb = b2[col];
      float cm = -1e38f;
#pragma unroll
      for (int r = 0; r < 4; ++r) {
#pragma unroll
        for (int i = 0; i < 4; ++i) {
          const int row = r*16 + lq*4 + i;
          const float v = (acc[r][c][i] + bb) * mk[row];
          outt[row*264 + col] = f2bf(v);
          cm = fmaxf(cm, v);
        }
      }
      cm = fmaxf(cm, __shfl_xor(cm, 16, 64));
      cm = fmaxf(cm, __shfl_xor(cm, 32, 64));
      if (lq == 0) poolpart[((size_t)(b*8 + seg))*256 + col] = cm;
    }
  }
  __syncthreads();
  // phase 3: GEMM3a (64 x 256, K=256) from outt; acc3 = h@W3a
  f32x4 acc3[4][4];
#pragma unroll
  for (int r = 0; r < 4; ++r)
#pragma unroll
    for (int c = 0; c < 4; ++c) acc3[r][c] = (f32x4){0.f,0.f,0.f,0.f};
#pragma unroll 2
  for (int kc = 0; kc < 256; kc += 32) {
    bf16x8 afr[4];
#pragma unroll
    for (int r = 0; r < 4; ++r)
      afr[r] = *(const bf16x8*)(outt + (r*16 + lr)*264 + kc + lq*8);
#pragma unroll
    for (int c = 0; c < 4; ++c) {
      const bf16x8 bfr = *(const bf16x8*)(W3t + (size_t)(wave*64 + c*16 + lr)*256 + kc + lq*8);
#pragma unroll
      for (int r = 0; r < 4; ++r)
        acc3[r][c] = __builtin_amdgcn_mfma_f32_16x16x32_bf16(afr[r], bfr, acc3[r][c], 0, 0, 0);
    }
  }
  __syncthreads();   // all waves done reading outt
  // epilogue: round acc3->bf16, stats partials on rounded values, write outt
#pragma unroll
  for (int c = 0; c < 4; ++c) {
    const int col = wave*64 + c*16 + lr;
    float sS = 0.f, sQ = 0.f;
#pragma unroll
    for (int r = 0; r < 4; ++r) {
#pragma unroll
      for (int i = 0; i < 4; ++i) {
        const int row = r*16 + lq*4 + i;
        const u16 w16 = f2bf(acc3[r][c][i]);
        const float w = bf2f(w16);
        outt[row*264 + col] = w16;
        sS += mk[row]*w;
        sQ += mk[row]*w*w;
      }
    }
    sS += __shfl_xor(sS, 16, 64);
    sS += __shfl_xor(sS, 32, 64);
    sQ += __shfl_xor(sQ, 16, 64);
    sQ += __shfl_xor(sQ, 32, 64);
    if (lq == 0) {
      s2sum[(size_t)rt*256 + col] = sS;
      s2sq [(size_t)rt*256 + col] = sQ;
    }
  }
  __syncthreads();
  // coalesced store acc3 tile -> global
  for (int it = tid; it < 64*32; it += 256) {
    const int row = it >> 5, c8 = it & 31;
    *(uint4*)(acc3buf + (size_t)(row0 + row)*256 + c8*8) = *(const uint4*)(outt + row*264 + c8*8);
  }
}

// ---------- pool reduce + P[b,:] = pooled[b]@W3[256:512] + b3 ----------
__global__ __launch_bounds__(256) void k_poolP(
    const float* __restrict__ poolpart, const float* __restrict__ W3,
    const float* __restrict__ b3, float* __restrict__ P) {
  __shared__ float pl[256];
  const int b = blockIdx.x, tid = threadIdx.x;
  float m = poolpart[((size_t)b*8)*256 + tid];
#pragma unroll
  for (int s = 1; s < 8; ++s) m = fmaxf(m, poolpart[((size_t)(b*8+s))*256 + tid]);
  pl[tid] = m;
  __syncthreads();
  float acc = b3[tid];
  for (int c = 0; c < 256; ++c) acc = fmaf(pl[c], W3[(size_t)(256 + c)*256 + tid], acc);
  P[(size_t)b*256 + tid] = acc;
}

// ---------- fold P into BN2 partials + reduce 512 batches -> 32 slabs ----------
__global__ __launch_bounds__(256) void k_red2(
    const float* __restrict__ s2sum, const float* __restrict__ s2sq,
    const int* __restrict__ cntpart, const float* __restrict__ P,
    float* __restrict__ midS, float* __restrict__ midQ) {
  const int slab = blockIdx.x;  // 0..31
  const int c = threadIdx.x;
  float accS = 0.f, accQ = 0.f;
  for (int b = slab*16; b < slab*16 + 16; ++b) {
    const float cntb = (float)(cntpart[4*b] + cntpart[4*b+1] + cntpart[4*b+2] + cntpart[4*b+3]);
    float S = 0.f, Q = 0.f;
#pragma unroll
    for (int s = 0; s < 8; ++s) {
      S += s2sum[(size_t)(b*8 + s)*256 + c];
      Q += s2sq [(size_t)(b*8 + s)*256 + c];
    }
    const float p = P[(size_t)b*256 + c];
    accS += fmaf(cntb, p, S);
    accQ += fmaf(cntb, p*p, fmaf(2.f*p, S, Q));
  }
  midS[slab*256 + c] = accS;
  midQ[slab*256 + c] = accQ;
}

// ---------- finalize BN2 ----------
__global__ __launch_bounds__(256) void k_fin2(
    const float* __restrict__ midS, const float* __restrict__ midQ,
    const float* __restrict__ cntf,
    const float* __restrict__ g2, const float* __restrict__ be2,
    float* __restrict__ a2, float* __restrict__ sh2) {
  const int c = threadIdx.x;
  float s = 0.f, q = 0.f;
#pragma unroll
  for (int k = 0; k < 32; ++k) { s += midS[k*256 + c]; q += midQ[k*256 + c]; }
  const float cf = *cntf;
  const float mean = s / cf;
  float var = q / cf - mean*mean; if (var < 0.f) var = 0.f;
  const float a = g2[c] * rsqrtf(var + EPSV);
  a2[c]  = a;
  sh2[c] = be2[c] - mean*a;
}

// ---------- GEMM4: z = relu((acc3+P)*a2+sh2); out-col-max of z@W4 + b4, masked ----------
__global__ __launch_bounds__(256, 4) void k_gemm4(
    const u16* __restrict__ acc3buf, const void* __restrict__ mask, const int* __restrict__ modep,
    const float* __restrict__ P, const float* __restrict__ a2, const float* __restrict__ sh2,
    const u16* __restrict__ W4t, const float* __restrict__ b4,
    float* __restrict__ outpart) {
  __shared__ u16 a2t[64*264];   // 33792 B  [row][k] pitch 264
  __shared__ float a2l[256], s2b[256];
  __shared__ float mk[64];
  const int mode = *modep;
  const int tid = threadIdx.x;
  const int rt = blockIdx.x;
  const int row0 = rt*64;
  const int b = rt >> 3, seg = rt & 7;
  if (tid < 64) mk[tid] = read_mask(mask, row0 + tid, mode);
  {  // fold P into shift: z = v*a2 + (P*a2 + sh2)
    const float aa = a2[tid];
    a2l[tid] = aa;
    s2b[tid] = fmaf(P[(size_t)b*256 + tid], aa, sh2[tid]);
  }
  __syncthreads();
  // stage + BN2 + ReLU -> a2t
  for (int it = tid; it < 64*32; it += 256) {
    const int row = it >> 5, c8 = it & 31;
    const uint4 u = *(const uint4*)(acc3buf + (size_t)(row0 + row)*256 + c8*8);
    const u16* us = (const u16*)&u;
    u16 z8[8];
#pragma unroll
    for (int j = 0; j < 8; ++j) {
      const int cc = c8*8 + j;
      const float z = fmaf(bf2f(us[j]), a2l[cc], s2b[cc]);
      z8[j] = f2bf(z > 0.f ? z : 0.f);
    }
    *(uint4*)(a2t + row*264 + c8*8) = *(const uint4*)z8;
  }
  __syncthreads();
  const int wave = tid >> 6, lane = tid & 63;
  const int lr = lane & 15, lq = lane >> 4;
  // GEMM4 (64 x 128, K=256); wave w: cols [32w, 32w+32)
  f32x4 acc2[4][2];
#pragma unroll
  for (int r = 0; r < 4; ++r)
#pragma unroll
    for (int c = 0; c < 2; ++c) acc2[r][c] = (f32x4){0.f,0.f,0.f,0.f};
#pragma unroll 2
  for (int kc = 0; kc < 256; kc += 32) {
    bf16x8 afr[4];
#pragma unroll
    for (int r = 0; r < 4; ++r)
      afr[r] = *(const bf16x8*)(a2t + (r*16 + lr)*264 + kc + lq*8);
#pragma unroll
    for (int c = 0; c < 2; ++c) {
      const bf16x8 bfr = *(const bf16x8*)(W4t + (size_t)(wave*32 + c*16 + lr)*256 + kc + lq*8);
#pragma unroll
      for (int r = 0; r < 4; ++r)
        acc2[r][c] = __builtin_amdgcn_mfma_f32_16x16x32_bf16(afr[r], bfr, acc2[r][c], 0, 0, 0);
    }
  }
#pragma unroll
  for (int c = 0; c < 2; ++c) {
    const int col = wave*32 + c*16 + lr;
    const float bb = b4[col];
    float cm = -1e38f;
#pragma unroll
    for (int r = 0; r < 4; ++r) {
#pragma unroll
      for (int i = 0; i < 4; ++i) {
        const int row = r*16 + lq*4 + i;
        cm = fmaxf(cm, (acc2[r][c][i] + bb) * mk[row]);
      }
    }
    cm = fmaxf(cm, __shfl_xor(cm, 16, 64));
    cm = fmaxf(cm, __shfl_xor(cm, 32, 64));
    if (lq == 0) outpart[((size_t)(b*8 + seg))*128 + col] = cm;
  }
}

// ---------- reduce 8 segment maxima -> out[b,e] ----------
__global__ __launch_bounds__(256) void k_outred(
    const float* __restrict__ outpart, float* __restrict__ out) {
  const int idx = blockIdx.x*256 + threadIdx.x;  // < 65536
  const int b = idx >> 7, e = idx & 127;
  float m = outpart[((size_t)b*8)*128 + e];
#pragma unroll
  for (int s = 1; s < 8; ++s) m = fmaxf(m, outpart[((size_t)(b*8 + s))*128 + e]);
  out[idx] = m;
}

extern "C" void kernel_launch(void* const* d_in, const int* in_sizes, int n_in,
                              void* d_out, int out_size, void* d_ws, size_t ws_size,
                              hipStream_t stream) {
  const float* x    = (const float*)d_in[0];
  const void*  mask = d_in[1];
  const float* W1   = (const float*)d_in[2];
  const float* b1   = (const float*)d_in[3];
  const float* g1   = (const float*)d_in[4];
  const float* be1  = (const float*)d_in[5];
  const float* W2   = (const float*)d_in[6];
  const float* b2   = (const float*)d_in[7];
  const float* W3   = (const float*)d_in[8];
  const float* b3   = (const float*)d_in[9];
  const float* g2   = (const float*)d_in[10];
  const float* be2  = (const float*)d_in[11];
  const float* W4   = (const float*)d_in[12];
  const float* b4   = (const float*)d_in[13];
  float* out = (float*)d_out;

  char* ws = (char*)d_ws;
  size_t off = 0;
  auto take = [&](size_t bytes) -> char* {
    char* p = ws + off;
    off = (off + bytes + 255) & ~(size_t)255;
    return p;
  };
  u16*   acc3buf = (u16*)  take((size_t)MROWS*256*2);   // 128 MiB
  float* s1sum   = (float*)take((size_t)2048*128*4);
  float* s1sq    = (float*)take((size_t)2048*128*4);
  int*   cntpart = (int*)  take((size_t)2048*4);
  float* mid1s   = (float*)take((size_t)16*128*4);
  float* mid1q   = (float*)take((size_t)16*128*4);
  float* w1p     = (float*)take(768*4);
  float* c1p     = (float*)take(128*4);
  float* cntf    = (float*)take(256);
  float* poolpart= (float*)take((size_t)512*8*256*4);
  float* P       = (float*)take((size_t)512*256*4);
  float* s2sum   = (float*)take((size_t)4096*256*4);
  float* s2sq    = (float*)take((size_t)4096*256*4);
  float* midS    = (float*)take((size_t)32*256*4);
  float* midQ    = (float*)take((size_t)32*256*4);
  float* a2      = (float*)take(256*4);
  float* sh2     = (float*)take(256*4);
  float* outpart = (float*)take((size_t)512*8*128*4);
  int*   modep   = (int*)  take(256);
  u16*   w2t     = (u16*)  take((size_t)256*128*2);
  u16*   w3t     = (u16*)  take((size_t)256*256*2);
  u16*   w4t     = (u16*)  take((size_t)128*256*2);

  k_detect<<<1, 256, 0, stream>>>((const unsigned char*)mask, modep);
  k_prep<<<512, 256, 0, stream>>>(W2, W3, W4, w2t, w3t, w4t);
  k_stats1<<<2048, 256, 0, stream>>>(x, mask, W1, b1, modep, s1sum, s1sq, cntpart);
  k_red1<<<16, 256, 0, stream>>>(s1sum, s1sq, mid1s, mid1q);
  k_fin1<<<1, 128, 0, stream>>>(mid1s, mid1q, cntpart, W1, b1, g1, be1, w1p, c1p, cntf);
  k_mega<<<RT, 256, 0, stream>>>(x, mask, modep, w1p, c1p, w2t, b2, w3t,
                                 acc3buf, poolpart, s2sum, s2sq);
  k_poolP<<<512, 256, 0, stream>>>(poolpart, W3, b3, P);
  k_red2<<<32, 256, 0, stream>>>(s2sum, s2sq, cntpart, P, midS, midQ);
  k_fin2<<<1, 256, 0, stream>>>(midS, midQ, cntf, g2, be2, a2, sh2);
  k_gemm4<<<RT, 256, 0, stream>>>(acc3buf, mask, modep, P, a2, sh2, w4t, b4, outpart);
  k_outred<<<256, 256, 0, stream>>>(outpart, out);
}